// Round 3
// baseline (10891.908 us; speedup 1.0000x reference)
//
#include <hip/hip_runtime.h>
#include <hip/hip_fp16.h>

#define BB 32
#define TIN 1024
#define FIN 80
#define CC 512
#define UU 512
#define GG 1536
#define VV 1024
#define TT 512
#define MM (BB*TT)   // 16384
#define EPS 1e-3f
#define NWDIR 128    // workgroups per direction in recurrence

// ---------------- conv1d(stride2,SAME) + bias + relu + BN -> f16 ----------------
__global__ __launch_bounds__(256) void conv_bn_k(
    const float* __restrict__ x, const float* __restrict__ w, const float* __restrict__ cb,
    const float* __restrict__ gam, const float* __restrict__ bet,
    const float* __restrict__ mu_, const float* __restrict__ var_,
    __half* __restrict__ out)
{
  __shared__ float xs[41*80];
  int tg = blockIdx.x;        // 32 groups of 16 t
  int b  = blockIdx.y;
  int ch = blockIdx.z;        // 0/1 channel half
  int t0 = tg*16;
  int in0 = t0*2 - 4;         // SAME pad_left = 4 (pad_total 9)
  for (int i = threadIdx.x; i < 41*80; i += 256) {
    int r = i / 80, f = i - r*80;
    int ri = in0 + r;
    xs[i] = (ri >= 0 && ri < TIN) ? x[((size_t)b*TIN + ri)*FIN + f] : 0.f;
  }
  __syncthreads();
  int c = ch*256 + threadIdx.x;
  float acc[16];
  float bv = cb[c];
#pragma unroll
  for (int i = 0; i < 16; i++) acc[i] = bv;
  for (int k = 0; k < 11; k++) {
    for (int f = 0; f < 80; f++) {
      float wv = w[((size_t)k*80 + f)*CC + c];
#pragma unroll
      for (int i = 0; i < 16; i++) acc[i] += xs[(2*i + k)*80 + f] * wv;
    }
  }
  float ga = gam[c], be = bet[c], mu = mu_[c], iv = rsqrtf(var_[c] + EPS);
#pragma unroll
  for (int i = 0; i < 16; i++) {
    float v = fmaxf(acc[i], 0.f);
    out[((size_t)b*TT + t0 + i)*CC + c] = __float2half(ga*(v - mu)*iv + be);
  }
}

// ---------------- fp32 SGEMM: C(M,N) = op(A)(M,K) @ Bw(K,N) + bias ----------------
template<int MODE, int OUTHALF>
__global__ __launch_bounds__(256) void sgemm_k(
    const __half* __restrict__ A0, const __half* __restrict__ A1,
    const float* __restrict__ gam, const float* __restrict__ bet,
    const float* __restrict__ mu_, const float* __restrict__ var_,
    const float* __restrict__ Bw, const float* __restrict__ bias,
    void* __restrict__ Cout, int M, int N, int K)
{
  __shared__ float As[8][128];
  __shared__ float Bs[8][128];
  int row0 = blockIdx.y * 128;
  int col0 = blockIdx.x * 128;
  int tid = threadIdx.x;
  int tx = tid & 15, ty = tid >> 4;
  float acc[8][8];
#pragma unroll
  for (int i=0;i<8;i++)
#pragma unroll
    for (int j=0;j<8;j++) acc[i][j]=0.f;
  int ar = tid >> 1;
  int akq = (tid & 1)*4;
  int bkr = tid >> 5;
  int bc = (tid & 31)*4;
  for (int k0 = 0; k0 < K; k0 += 8) {
    size_t aoff = (size_t)(row0+ar)*K + k0 + akq;
    float2 lo = __half22float2(*(const __half2*)(A0 + aoff));
    float2 hi = __half22float2(*(const __half2*)(A0 + aoff + 2));
    float4 a; a.x=lo.x; a.y=lo.y; a.z=hi.x; a.w=hi.y;
    if (MODE >= 1) {
      float2 l1 = __half22float2(*(const __half2*)(A1 + aoff));
      float2 h1 = __half22float2(*(const __half2*)(A1 + aoff + 2));
      a.x+=l1.x; a.y+=l1.y; a.z+=h1.x; a.w+=h1.y;
    }
    if (MODE == 2) {
      int kk = k0 + akq;
      float4 g4 = *(const float4*)(gam+kk);
      float4 b4 = *(const float4*)(bet+kk);
      float4 m4 = *(const float4*)(mu_+kk);
      float4 v4 = *(const float4*)(var_+kk);
      a.x = g4.x*(a.x-m4.x)*rsqrtf(v4.x+EPS)+b4.x;
      a.y = g4.y*(a.y-m4.y)*rsqrtf(v4.y+EPS)+b4.y;
      a.z = g4.z*(a.z-m4.z)*rsqrtf(v4.z+EPS)+b4.z;
      a.w = g4.w*(a.w-m4.w)*rsqrtf(v4.w+EPS)+b4.w;
    }
    As[akq+0][ar]=a.x; As[akq+1][ar]=a.y; As[akq+2][ar]=a.z; As[akq+3][ar]=a.w;
    *(float4*)&Bs[bkr][bc] = *(const float4*)(Bw + (size_t)(k0+bkr)*N + col0 + bc);
    __syncthreads();
#pragma unroll
    for (int kk = 0; kk < 8; kk++) {
      float ar8[8], br8[8];
      *(float4*)&ar8[0] = *(const float4*)&As[kk][ty*8];
      *(float4*)&ar8[4] = *(const float4*)&As[kk][ty*8+4];
      *(float4*)&br8[0] = *(const float4*)&Bs[kk][tx*8];
      *(float4*)&br8[4] = *(const float4*)&Bs[kk][tx*8+4];
#pragma unroll
      for (int i=0;i<8;i++)
#pragma unroll
        for (int j=0;j<8;j++) acc[i][j] += ar8[i]*br8[j];
    }
    __syncthreads();
  }
#pragma unroll
  for (int i=0;i<8;i++) {
    int r = row0 + ty*8 + i;
#pragma unroll
    for (int j=0;j<8;j++) {
      int c2 = col0 + tx*8 + j;
      float v = acc[i][j] + bias[c2];
      if (OUTHALF) ((__half*)Cout)[(size_t)r*N + c2] = __float2half(v);
      else         ((float*)Cout)[(size_t)r*N + c2] = v;
    }
  }
}

// ---------------- persistent bidirectional GRU layer (f16 exchange) ----------------
// 256 WGs (128/dir), 256 thr. WG owns u-slice [wg*4, wg*4+4).
// Wh slice lives in REGISTERS (96 f32/thread). h exchanged as f16 via
// device-coherent (sc0 sc1) stores/loads; flag-array barrier (stores only,
// no atomic RMW contention). Recurrence carry hreg stays f32.
__device__ __forceinline__ float2 cvt2(unsigned int u) {
  __half2 h = *(__half2*)&u;
  return __half22float2(h);
}

__global__ __launch_bounds__(256,1) void gru_layer_k(
    const __half* __restrict__ xgf, const __half* __restrict__ xgb,
    const float* __restrict__ whf, const float* __restrict__ whb,
    const float* __restrict__ brf, const float* __restrict__ brb,
    __half* __restrict__ hsf, __half* __restrict__ hsb,
    unsigned short* __restrict__ hb, unsigned int* __restrict__ flags)
{
  int wg  = blockIdx.x & (NWDIR-1);
  int dir = blockIdx.x >> 7;
  const __half* xg = dir ? xgb : xgf;
  const float* wh  = dir ? whb : whf;
  const float* brc = dir ? brb : brf;
  __half* hs = dir ? hsb : hsf;
  unsigned short* hbd = hb + (size_t)dir * 2 * 32 * 512;  // f16 ping-pong [2][32][512]
  unsigned int* arr = flags + dir * NWDIR;
  int tid = threadIdx.x;
  int u0 = wg * 4;

  __shared__ unsigned short hsl[32*520];   // h staged f16, padded+swizzled rows
  __shared__ float S[16*12*33];            // k-partials [kh][col(g*4+uu)][b]

  // ---- Wh slice -> registers: thread (bq,uu,kh) holds 3 cols x 32 k ----
  int bq = tid & 3, uu = (tid >> 2) & 3, kh = tid >> 4;   // kh 0..15
  float wr[3][32];
#pragma unroll
  for (int c = 0; c < 3; c++) {
    int col = c*512 + u0 + uu;
#pragma unroll
    for (int i = 0; i < 32; i++)
      wr[c][i] = wh[(size_t)(kh*32 + i)*GG + col];
  }

  // ---- gate-phase mapping (tid<64): b=tid&31, u-pair up=tid>>5 ----
  int gb = tid & 31, up = (tid >> 5) & 1;
  float br_[3][2];
  float hreg[2] = {0.f, 0.f};
  unsigned int xz_r = 0, xr_r = 0, xh_r = 0;   // prefetched xg (packed f16 pairs)
  if (tid < 64) {
    int u = u0 + 2*up;
#pragma unroll
    for (int g = 0; g < 3; g++) { br_[g][0] = brc[g*512+u]; br_[g][1] = brc[g*512+u+1]; }
    // publish h0 = 0 into ping buffer 0 (device-coherent)
    __hip_atomic_store((unsigned int*)hbd + gb*256 + wg*2 + up, 0u,
                       __ATOMIC_RELAXED, __HIP_MEMORY_SCOPE_AGENT);
    // prefetch xg for s=0
    int t0_ = dir ? 511 : 0;
    const unsigned int* xp = (const unsigned int*)xg + ((size_t)gb*TT + t0_)*768;
    xz_r = xp[0*256 + wg*2 + up];
    xr_r = xp[1*256 + wg*2 + up];
    xh_r = xp[2*256 + wg*2 + up];
  }

  // ---- broadcast-stage mapping: thread covers 128B contiguous of hb ----
  int srow = tid & 31;          // h row (b)
  int sg8  = tid >> 5;          // 0..7 : which 128B chunk of the row
  int swz  = (srow >> 3) & 3;   // granule low-2-bit XOR (matches read k8^bq)
  int wbase = srow*520;

  for (int s = 0; s < 512; s++) {
    __syncthreads();   // drains vmcnt(0): our sc0sc1 h stores are at coherence point
    if (tid == 0)
      __hip_atomic_store(&arr[wg], (unsigned int)(s+1),
                         __ATOMIC_RELAXED, __HIP_MEMORY_SCOPE_AGENT);
    if (tid < NWDIR) {
      long guard = 0;
      while (__hip_atomic_load(&arr[tid], __ATOMIC_RELAXED, __HIP_MEMORY_SCOPE_AGENT)
             < (unsigned int)(s+1)) {
        if (++guard > 5000000L) break;   // bailout: wrong answer, no hang
      }
    }
    __syncthreads();
    int p = s & 1;
    // ---- broadcast h (32KB f16) : 8 coherent b128 loads, one drain ----
    {
      const unsigned short* gp = hbd + p*16384 + srow*512 + sg8*64;
      float4 t0,t1,t2,t3,t4,t5,t6,t7;
      asm volatile(
        "global_load_dwordx4 %0, %8, off sc0 sc1\n\t"
        "global_load_dwordx4 %1, %8, off offset:16 sc0 sc1\n\t"
        "global_load_dwordx4 %2, %8, off offset:32 sc0 sc1\n\t"
        "global_load_dwordx4 %3, %8, off offset:48 sc0 sc1\n\t"
        "global_load_dwordx4 %4, %8, off offset:64 sc0 sc1\n\t"
        "global_load_dwordx4 %5, %8, off offset:80 sc0 sc1\n\t"
        "global_load_dwordx4 %6, %8, off offset:96 sc0 sc1\n\t"
        "global_load_dwordx4 %7, %8, off offset:112 sc0 sc1\n\t"
        "s_waitcnt vmcnt(0)"
        : "=&v"(t0),"=&v"(t1),"=&v"(t2),"=&v"(t3),
          "=&v"(t4),"=&v"(t5),"=&v"(t6),"=&v"(t7)
        : "v"(gp) : "memory");
      int g0 = sg8*8;
      *(float4*)&hsl[wbase + ((g0+0)^swz)*8] = t0;
      *(float4*)&hsl[wbase + ((g0+1)^swz)*8] = t1;
      *(float4*)&hsl[wbase + ((g0+2)^swz)*8] = t2;
      *(float4*)&hsl[wbase + ((g0+3)^swz)*8] = t3;
      *(float4*)&hsl[wbase + ((g0+4)^swz)*8] = t4;
      *(float4*)&hsl[wbase + ((g0+5)^swz)*8] = t5;
      *(float4*)&hsl[wbase + ((g0+6)^swz)*8] = t6;
      *(float4*)&hsl[wbase + ((g0+7)^swz)*8] = t7;
    }
    __syncthreads();
    // ---- rg partial: rows bq*8..+7, cols 3, k slice kh*32..+31 ----
    float acc[3][8];
#pragma unroll
    for (int c = 0; c < 3; c++)
#pragma unroll
      for (int r = 0; r < 8; r++) acc[c][r] = 0.f;
#pragma unroll
    for (int k8 = 0; k8 < 4; k8++) {
      int coff = kh*32 + ((k8 ^ bq) << 3);
      uint4 hv[8];
#pragma unroll
      for (int r = 0; r < 8; r++)
        hv[r] = *(const uint4*)&hsl[(bq*8+r)*520 + coff];
#pragma unroll
      for (int r = 0; r < 8; r++) {
        float2 f0 = cvt2(hv[r].x), f1 = cvt2(hv[r].y);
        float2 f2 = cvt2(hv[r].z), f3 = cvt2(hv[r].w);
        float hf[8] = {f0.x,f0.y,f1.x,f1.y,f2.x,f2.y,f3.x,f3.y};
#pragma unroll
        for (int c = 0; c < 3; c++) {
#pragma unroll
          for (int kk = 0; kk < 8; kk++)
            acc[c][r] += wr[c][k8*8+kk] * hf[kk];
        }
      }
    }
#pragma unroll
    for (int c = 0; c < 3; c++)
#pragma unroll
      for (int r = 0; r < 8; r++)
        S[((kh*3 + c)*4 + uu)*33 + bq*8 + r] = acc[c][r];
    __syncthreads();
    // ---- gates: tid<64, each handles (b, 2 u's) ----
    if (tid < 64) {
      int t = dir ? (511 - s) : s;
      float rg[3][2] = {{br_[0][0],br_[0][1]},{br_[1][0],br_[1][1]},{br_[2][0],br_[2][1]}};
#pragma unroll
      for (int q = 0; q < 16; q++)
#pragma unroll
        for (int g = 0; g < 3; g++) {
          rg[g][0] += S[((q*3+g)*4 + 2*up+0)*33 + gb];
          rg[g][1] += S[((q*3+g)*4 + 2*up+1)*33 + gb];
        }
      float2 xzv = cvt2(xz_r), xrv = cvt2(xr_r), xhv = cvt2(xh_r);
      float xzf[2] = {xzv.x,xzv.y}, xrf[2] = {xrv.x,xrv.y}, xhf[2] = {xhv.x,xhv.y};
#pragma unroll
      for (int e = 0; e < 2; e++) {
        float z = 1.f/(1.f + __expf(-(xzf[e] + rg[0][e])));
        float r = 1.f/(1.f + __expf(-(xrf[e] + rg[1][e])));
        float hh = fmaxf(xhf[e] + r*rg[2][e], 0.f);
        hreg[e] = z*hreg[e] + (1.f - z)*hh;
      }
      __half2 hp2 = __floats2half2_rn(hreg[0], hreg[1]);
      unsigned int pk = *(unsigned int*)&hp2;
      __hip_atomic_store((unsigned int*)hbd + (1-p)*8192 + gb*256 + wg*2 + up, pk,
                         __ATOMIC_RELAXED, __HIP_MEMORY_SCOPE_AGENT);
      *((unsigned int*)hs + (size_t)(gb*TT + t)*256 + wg*2 + up) = pk;  // seq output
      // prefetch xg for s+1
      int tn = (dir ? (510 - s) : (s + 1)) & 511;
      const unsigned int* xp = (const unsigned int*)xg + ((size_t)gb*TT + tn)*768;
      xz_r = xp[0*256 + wg*2 + up];
      xr_r = xp[1*256 + wg*2 + up];
      xh_r = xp[2*256 + wg*2 + up];
    }
  }
}

// ---------------- row softmax over V=1024, in place ----------------
__global__ __launch_bounds__(256) void softmax_k(float* __restrict__ p) {
  size_t row = blockIdx.x;
  float* pr = p + row*VV;
  int tid = threadIdx.x;
  float4 v = ((float4*)pr)[tid];
  float m = fmaxf(fmaxf(v.x, v.y), fmaxf(v.z, v.w));
#pragma unroll
  for (int o = 32; o >= 1; o >>= 1) m = fmaxf(m, __shfl_xor(m, o));
  __shared__ float red[4];
  __shared__ float red2[4];
  int w = tid >> 6;
  if ((tid & 63) == 0) red[w] = m;
  __syncthreads();
  m = fmaxf(fmaxf(red[0], red[1]), fmaxf(red[2], red[3]));
  v.x = __expf(v.x - m); v.y = __expf(v.y - m);
  v.z = __expf(v.z - m); v.w = __expf(v.w - m);
  float s = v.x + v.y + v.z + v.w;
#pragma unroll
  for (int o = 32; o >= 1; o >>= 1) s += __shfl_xor(s, o);
  if ((tid & 63) == 0) red2[w] = s;
  __syncthreads();
  s = red2[0] + red2[1] + red2[2] + red2[3];
  float inv = 1.f / s;
  v.x *= inv; v.y *= inv; v.z *= inv; v.w *= inv;
  ((float4*)pr)[tid] = v;
}

extern "C" void kernel_launch(void* const* d_in, const int* in_sizes, int n_in,
                              void* d_out, int out_size, void* d_ws, size_t ws_size,
                              hipStream_t stream) {
  const float* x      = (const float*)d_in[0];
  const float* conv_w = (const float*)d_in[1];
  const float* conv_b = (const float*)d_in[2];
  const float* wx_f   = (const float*)d_in[3];
  const float* wh_f   = (const float*)d_in[4];
  const float* bi_f   = (const float*)d_in[5];
  const float* br_f   = (const float*)d_in[6];
  const float* wx_b   = (const float*)d_in[7];
  const float* wh_b   = (const float*)d_in[8];
  const float* bi_b   = (const float*)d_in[9];
  const float* br_b   = (const float*)d_in[10];
  const float* gam    = (const float*)d_in[11];
  const float* bet    = (const float*)d_in[12];
  const float* mu_    = (const float*)d_in[13];
  const float* var_   = (const float*)d_in[14];
  const float* dw     = (const float*)d_in[15];
  const float* db     = (const float*)d_in[16];

  char* ws = (char*)d_ws;
  __half* c0   = (__half*)(ws + 0);                 // 16,777,216  (conv/BN out; later hs2_f)
  __half* xgf  = (__half*)(ws + 16777216LL);        // 50,331,648
  __half* xgb  = (__half*)(ws + 67108864LL);        // 50,331,648
  __half* hs1f = (__half*)(ws + 117440512LL);       // 16,777,216  (later hs2_b)
  __half* hs1b = (__half*)(ws + 134217728LL);       // 16,777,216
  unsigned short* hb = (unsigned short*)(ws + 150994944LL);  // 131,072 (f16 ping-pong)
  unsigned int* flags = (unsigned int*)(ws + 151126016LL);   // 2,048 (2 layers x 2 dirs x 128)
  if (ws_size < 151128064ULL) return;
  __half* hs2f = c0;
  __half* hs2b = hs1f;
  float* logits = (float*)d_out;

  hipMemsetAsync(flags, 0, 2048, stream);

  dim3 cg(32, 32, 2);
  conv_bn_k<<<cg, 256, 0, stream>>>(x, conv_w, conv_b, gam, bet, mu_, var_, c0);

  dim3 g1(12, 128);  // N/128, M/128 for N=1536
  sgemm_k<0,1><<<g1, 256, 0, stream>>>(c0, nullptr, nullptr,nullptr,nullptr,nullptr,
                                       wx_f, bi_f, xgf, MM, GG, CC);
  sgemm_k<0,1><<<g1, 256, 0, stream>>>(c0, nullptr, nullptr,nullptr,nullptr,nullptr,
                                       wx_b, bi_b, xgb, MM, GG, CC);
  gru_layer_k<<<256, 256, 0, stream>>>(xgf, xgb, wh_f, wh_b, br_f, br_b,
                                       hs1f, hs1b, hb, flags);
  sgemm_k<1,1><<<g1, 256, 0, stream>>>(hs1f, hs1b, nullptr,nullptr,nullptr,nullptr,
                                       wx_f, bi_f, xgf, MM, GG, CC);
  sgemm_k<1,1><<<g1, 256, 0, stream>>>(hs1f, hs1b, nullptr,nullptr,nullptr,nullptr,
                                       wx_b, bi_b, xgb, MM, GG, CC);
  gru_layer_k<<<256, 256, 0, stream>>>(xgf, xgb, wh_f, wh_b, br_f, br_b,
                                       hs2f, hs2b, hb, flags + 256);
  dim3 g2(8, 128);   // N=1024
  sgemm_k<2,0><<<g2, 256, 0, stream>>>(hs2f, hs2b, gam, bet, mu_, var_,
                                       dw, db, logits, MM, VV, CC);
  softmax_k<<<MM, 256, 0, stream>>>(logits);
}

// Round 4
// 7187.283 us; speedup vs baseline: 1.5154x; 1.5154x over previous
//
#include <hip/hip_runtime.h>
#include <hip/hip_fp16.h>

#define BB 32
#define TIN 1024
#define FIN 80
#define CC 512
#define UU 512
#define GG 1536
#define VV 1024
#define TT 512
#define MM (BB*TT)   // 16384
#define EPS 1e-3f
#define NWDIR 128    // workgroups per direction in recurrence

typedef _Float16 f16x2 __attribute__((ext_vector_type(2)));
__device__ __forceinline__ f16x2 asf16x2(unsigned u) {
  union { unsigned u; f16x2 h; } v; v.u = u; return v.h;
}
__device__ __forceinline__ float fdot2_(f16x2 a, f16x2 b, float c) {
#if __has_builtin(__builtin_amdgcn_fdot2)
  return __builtin_amdgcn_fdot2(a, b, c, false);
#else
  return c + (float)a[0]*(float)b[0] + (float)a[1]*(float)b[1];
#endif
}

// ---------------- conv1d(stride2,SAME) + bias + relu + BN -> f16 ----------------
__global__ __launch_bounds__(256) void conv_bn_k(
    const float* __restrict__ x, const float* __restrict__ w, const float* __restrict__ cb,
    const float* __restrict__ gam, const float* __restrict__ bet,
    const float* __restrict__ mu_, const float* __restrict__ var_,
    __half* __restrict__ out)
{
  __shared__ float xs[41*80];
  int tg = blockIdx.x;        // 32 groups of 16 t
  int b  = blockIdx.y;
  int ch = blockIdx.z;        // 0/1 channel half
  int t0 = tg*16;
  int in0 = t0*2 - 4;         // SAME pad_left = 4 (pad_total 9)
  for (int i = threadIdx.x; i < 41*80; i += 256) {
    int r = i / 80, f = i - r*80;
    int ri = in0 + r;
    xs[i] = (ri >= 0 && ri < TIN) ? x[((size_t)b*TIN + ri)*FIN + f] : 0.f;
  }
  __syncthreads();
  int c = ch*256 + threadIdx.x;
  float acc[16];
  float bv = cb[c];
#pragma unroll
  for (int i = 0; i < 16; i++) acc[i] = bv;
  for (int k = 0; k < 11; k++) {
    for (int f = 0; f < 80; f++) {
      float wv = w[((size_t)k*80 + f)*CC + c];
#pragma unroll
      for (int i = 0; i < 16; i++) acc[i] += xs[(2*i + k)*80 + f] * wv;
    }
  }
  float ga = gam[c], be = bet[c], mu = mu_[c], iv = rsqrtf(var_[c] + EPS);
#pragma unroll
  for (int i = 0; i < 16; i++) {
    float v = fmaxf(acc[i], 0.f);
    out[((size_t)b*TT + t0 + i)*CC + c] = __float2half(ga*(v - mu)*iv + be);
  }
}

// ---------------- fp32 SGEMM: C(M,N) = op(A)(M,K) @ Bw(K,N) + bias ----------------
template<int MODE, int OUTHALF>
__global__ __launch_bounds__(256) void sgemm_k(
    const __half* __restrict__ A0, const __half* __restrict__ A1,
    const float* __restrict__ gam, const float* __restrict__ bet,
    const float* __restrict__ mu_, const float* __restrict__ var_,
    const float* __restrict__ Bw, const float* __restrict__ bias,
    void* __restrict__ Cout, int M, int N, int K)
{
  __shared__ float As[8][128];
  __shared__ float Bs[8][128];
  int row0 = blockIdx.y * 128;
  int col0 = blockIdx.x * 128;
  int tid = threadIdx.x;
  int tx = tid & 15, ty = tid >> 4;
  float acc[8][8];
#pragma unroll
  for (int i=0;i<8;i++)
#pragma unroll
    for (int j=0;j<8;j++) acc[i][j]=0.f;
  int ar = tid >> 1;
  int akq = (tid & 1)*4;
  int bkr = tid >> 5;
  int bc = (tid & 31)*4;
  for (int k0 = 0; k0 < K; k0 += 8) {
    size_t aoff = (size_t)(row0+ar)*K + k0 + akq;
    float2 lo = __half22float2(*(const __half2*)(A0 + aoff));
    float2 hi = __half22float2(*(const __half2*)(A0 + aoff + 2));
    float4 a; a.x=lo.x; a.y=lo.y; a.z=hi.x; a.w=hi.y;
    if (MODE >= 1) {
      float2 l1 = __half22float2(*(const __half2*)(A1 + aoff));
      float2 h1 = __half22float2(*(const __half2*)(A1 + aoff + 2));
      a.x+=l1.x; a.y+=l1.y; a.z+=h1.x; a.w+=h1.y;
    }
    if (MODE == 2) {
      int kk = k0 + akq;
      float4 g4 = *(const float4*)(gam+kk);
      float4 b4 = *(const float4*)(bet+kk);
      float4 m4 = *(const float4*)(mu_+kk);
      float4 v4 = *(const float4*)(var_+kk);
      a.x = g4.x*(a.x-m4.x)*rsqrtf(v4.x+EPS)+b4.x;
      a.y = g4.y*(a.y-m4.y)*rsqrtf(v4.y+EPS)+b4.y;
      a.z = g4.z*(a.z-m4.z)*rsqrtf(v4.z+EPS)+b4.z;
      a.w = g4.w*(a.w-m4.w)*rsqrtf(v4.w+EPS)+b4.w;
    }
    As[akq+0][ar]=a.x; As[akq+1][ar]=a.y; As[akq+2][ar]=a.z; As[akq+3][ar]=a.w;
    *(float4*)&Bs[bkr][bc] = *(const float4*)(Bw + (size_t)(k0+bkr)*N + col0 + bc);
    __syncthreads();
#pragma unroll
    for (int kk = 0; kk < 8; kk++) {
      float ar8[8], br8[8];
      *(float4*)&ar8[0] = *(const float4*)&As[kk][ty*8];
      *(float4*)&ar8[4] = *(const float4*)&As[kk][ty*8+4];
      *(float4*)&br8[0] = *(const float4*)&Bs[kk][tx*8];
      *(float4*)&br8[4] = *(const float4*)&Bs[kk][tx*8+4];
#pragma unroll
      for (int i=0;i<8;i++)
#pragma unroll
        for (int j=0;j<8;j++) acc[i][j] += ar8[i]*br8[j];
    }
    __syncthreads();
  }
#pragma unroll
  for (int i=0;i<8;i++) {
    int r = row0 + ty*8 + i;
#pragma unroll
    for (int j=0;j<8;j++) {
      int c2 = col0 + tx*8 + j;
      float v = acc[i][j] + bias[c2];
      if (OUTHALF) ((__half*)Cout)[(size_t)r*N + c2] = __float2half(v);
      else         ((float*)Cout)[(size_t)r*N + c2] = v;
    }
  }
}

// ---------------- persistent bidirectional GRU layer (f16 exchange, dot2) -------
// 256 WGs (128/dir), 256 thr. WG owns u-slice [wg*4, wg*4+4).
// Wh slice in REGISTERS as packed f16 (48 VGPRs). h exchanged as f16 via
// device-coherent (sc0 sc1) stores/loads. Barrier: striped counters (4 lines),
// arrival = 1 relaxed agent RMW per WG, detection = tid0 4-load poll with
// s_sleep backoff (low L3 traffic). Recurrence carry hreg stays f32.
__global__ __launch_bounds__(256,1) void gru_layer_k(
    const __half* __restrict__ xgf, const __half* __restrict__ xgb,
    const float* __restrict__ whf, const float* __restrict__ whb,
    const float* __restrict__ brf, const float* __restrict__ brb,
    __half* __restrict__ hsf, __half* __restrict__ hsb,
    unsigned short* __restrict__ hb, unsigned int* __restrict__ flags)
{
  int wg  = blockIdx.x & (NWDIR-1);
  int dir = blockIdx.x >> 7;
  const __half* xg = dir ? xgb : xgf;
  const float* wh  = dir ? whb : whf;
  const float* brc = dir ? brb : brf;
  __half* hs = dir ? hsb : hsf;
  unsigned short* hbd = hb + (size_t)dir * 2 * 32 * 512;  // f16 ping-pong [2][32][512]
  unsigned int* c4 = flags + dir * 64;                    // 4 counters, 64B apart
  int tid = threadIdx.x;
  int u0 = wg * 4;

  __shared__ unsigned short hsl[32*520];   // h staged f16, padded+swizzled granules
  __shared__ float S[16*12*33];            // k-partials [kh][col(g*4+uu)][b]

  // ---- Wh slice -> registers (packed f16): thread (bq,uu,kh): 3 cols x 32 k ----
  int bq = tid & 3, uu = (tid >> 2) & 3, kh = tid >> 4;   // kh 0..15
  unsigned wpk[3][16];
#pragma unroll
  for (int c = 0; c < 3; c++) {
    int col = c*512 + u0 + uu;
#pragma unroll
    for (int i = 0; i < 16; i++) {
      float w0 = wh[(size_t)(kh*32 + 2*i  )*GG + col];
      float w1 = wh[(size_t)(kh*32 + 2*i+1)*GG + col];
      __half2 h2 = __floats2half2_rn(w0, w1);
      wpk[c][i] = *(unsigned*)&h2;
    }
  }

  // ---- gate-phase mapping (tid<64): b=tid&31, u-pair up=tid>>5 ----
  int gb = tid & 31, up = (tid >> 5) & 1;
  float br_[3][2];
  float hreg[2] = {0.f, 0.f};
  unsigned int xz_r = 0, xr_r = 0, xh_r = 0;   // prefetched xg (packed f16 pairs)
  if (tid < 64) {
    int u = u0 + 2*up;
#pragma unroll
    for (int g = 0; g < 3; g++) { br_[g][0] = brc[g*512+u]; br_[g][1] = brc[g*512+u+1]; }
    // publish h0 = 0 into ping buffer 0 (device-coherent)
    __hip_atomic_store((unsigned int*)hbd + gb*256 + wg*2 + up, 0u,
                       __ATOMIC_RELAXED, __HIP_MEMORY_SCOPE_AGENT);
    // prefetch xg for s=0
    int t0_ = dir ? 511 : 0;
    const unsigned int* xp = (const unsigned int*)xg + ((size_t)gb*TT + t0_)*768;
    xz_r = xp[0*256 + wg*2 + up];
    xr_r = xp[1*256 + wg*2 + up];
    xh_r = xp[2*256 + wg*2 + up];
  }

  // ---- broadcast-stage mapping: instr j is 1KB lane-contiguous ----
  int wv = tid >> 6;            // wave id 0..3
  int cg = tid & 63;            // logical granule (8 halfs) within row

  for (int s = 0; s < 512; s++) {
    __syncthreads();   // drains vmcnt(0): our sc0sc1 h stores are at coherence point
    if (tid == 0) {
      __hip_atomic_fetch_add(&c4[(wg & 3) * 16], 1u,
                             __ATOMIC_RELAXED, __HIP_MEMORY_SCOPE_AGENT);
      unsigned tgt = (unsigned)(s + 1) * (unsigned)NWDIR;
      long guard = 0;
      for (;;) {
        unsigned v0 = __hip_atomic_load(&c4[0],  __ATOMIC_RELAXED, __HIP_MEMORY_SCOPE_AGENT);
        unsigned v1 = __hip_atomic_load(&c4[16], __ATOMIC_RELAXED, __HIP_MEMORY_SCOPE_AGENT);
        unsigned v2 = __hip_atomic_load(&c4[32], __ATOMIC_RELAXED, __HIP_MEMORY_SCOPE_AGENT);
        unsigned v3 = __hip_atomic_load(&c4[48], __ATOMIC_RELAXED, __HIP_MEMORY_SCOPE_AGENT);
        if (v0 + v1 + v2 + v3 >= tgt) break;
        if (++guard > 5000000L) break;   // bailout: wrong answer, no hang
        __builtin_amdgcn_s_sleep(1);
      }
    }
    __syncthreads();
    int p = s & 1;
    // ---- broadcast h (32KB f16): 8 coherent b128 loads, 1KB contiguous each ----
    {
      const unsigned short* g0 = hbd + p*16384 + tid*8;
      float4 t0,t1,t2,t3,t4,t5,t6,t7;
      asm volatile(
        "global_load_dwordx4 %0, %8, off sc0 sc1\n\t"
        "global_load_dwordx4 %1, %9, off sc0 sc1\n\t"
        "global_load_dwordx4 %2, %10, off sc0 sc1\n\t"
        "global_load_dwordx4 %3, %11, off sc0 sc1\n\t"
        "global_load_dwordx4 %4, %12, off sc0 sc1\n\t"
        "global_load_dwordx4 %5, %13, off sc0 sc1\n\t"
        "global_load_dwordx4 %6, %14, off sc0 sc1\n\t"
        "global_load_dwordx4 %7, %15, off sc0 sc1\n\t"
        "s_waitcnt vmcnt(0)"
        : "=&v"(t0),"=&v"(t1),"=&v"(t2),"=&v"(t3),
          "=&v"(t4),"=&v"(t5),"=&v"(t6),"=&v"(t7)
        : "v"(g0),"v"(g0+2048),"v"(g0+4096),"v"(g0+6144),
          "v"(g0+8192),"v"(g0+10240),"v"(g0+12288),"v"(g0+14336)
        : "memory");
      // store: instr j -> row j*4+wv, granule cg ^ ((j>>1)&3)   (swz=(row>>3)&3)
      *(float4*)&hsl[((0*4+wv))*520 + ((cg ^ 0)<<3)] = t0;
      *(float4*)&hsl[((1*4+wv))*520 + ((cg ^ 0)<<3)] = t1;
      *(float4*)&hsl[((2*4+wv))*520 + ((cg ^ 1)<<3)] = t2;
      *(float4*)&hsl[((3*4+wv))*520 + ((cg ^ 1)<<3)] = t3;
      *(float4*)&hsl[((4*4+wv))*520 + ((cg ^ 2)<<3)] = t4;
      *(float4*)&hsl[((5*4+wv))*520 + ((cg ^ 2)<<3)] = t5;
      *(float4*)&hsl[((6*4+wv))*520 + ((cg ^ 3)<<3)] = t6;
      *(float4*)&hsl[((7*4+wv))*520 + ((cg ^ 3)<<3)] = t7;
    }
    __syncthreads();
    // ---- rg partial: rows bq*8..+7, 3 cols, k slice kh*32..+31, via dot2 ----
    float acc[3][8];
#pragma unroll
    for (int c = 0; c < 3; c++)
#pragma unroll
      for (int r = 0; r < 8; r++) acc[c][r] = 0.f;
#pragma unroll
    for (int k8 = 0; k8 < 4; k8++) {
      int coff = kh*32 + ((k8 ^ bq) << 3);   // physical granule = logical ^ bq
      uint4 hv[8];
#pragma unroll
      for (int r = 0; r < 8; r++)
        hv[r] = *(const uint4*)&hsl[(bq*8+r)*520 + coff];
#pragma unroll
      for (int r = 0; r < 8; r++) {
        f16x2 h0 = asf16x2(hv[r].x), h1 = asf16x2(hv[r].y);
        f16x2 h2 = asf16x2(hv[r].z), h3 = asf16x2(hv[r].w);
#pragma unroll
        for (int c = 0; c < 3; c++) {
          float a = acc[c][r];
          a = fdot2_(h0, asf16x2(wpk[c][k8*4+0]), a);
          a = fdot2_(h1, asf16x2(wpk[c][k8*4+1]), a);
          a = fdot2_(h2, asf16x2(wpk[c][k8*4+2]), a);
          a = fdot2_(h3, asf16x2(wpk[c][k8*4+3]), a);
          acc[c][r] = a;
        }
      }
    }
#pragma unroll
    for (int c = 0; c < 3; c++)
#pragma unroll
      for (int r = 0; r < 8; r++)
        S[((kh*3 + c)*4 + uu)*33 + bq*8 + r] = acc[c][r];
    __syncthreads();
    // ---- gates: tid<64, each handles (b, 2 u's) ----
    if (tid < 64) {
      int t = dir ? (511 - s) : s;
      float rg[3][2] = {{br_[0][0],br_[0][1]},{br_[1][0],br_[1][1]},{br_[2][0],br_[2][1]}};
#pragma unroll
      for (int q = 0; q < 16; q++)
#pragma unroll
        for (int g = 0; g < 3; g++) {
          rg[g][0] += S[((q*3+g)*4 + 2*up+0)*33 + gb];
          rg[g][1] += S[((q*3+g)*4 + 2*up+1)*33 + gb];
        }
      __half2 xzh = *(__half2*)&xz_r, xrh = *(__half2*)&xr_r, xhh = *(__half2*)&xh_r;
      float2 xzv = __half22float2(xzh), xrv = __half22float2(xrh), xhv = __half22float2(xhh);
      float xzf[2] = {xzv.x,xzv.y}, xrf[2] = {xrv.x,xrv.y}, xhf[2] = {xhv.x,xhv.y};
#pragma unroll
      for (int e = 0; e < 2; e++) {
        float z = 1.f/(1.f + __expf(-(xzf[e] + rg[0][e])));
        float r = 1.f/(1.f + __expf(-(xrf[e] + rg[1][e])));
        float hh = fmaxf(xhf[e] + r*rg[2][e], 0.f);
        hreg[e] = z*hreg[e] + (1.f - z)*hh;
      }
      __half2 hp2 = __floats2half2_rn(hreg[0], hreg[1]);
      unsigned int pk = *(unsigned int*)&hp2;
      __hip_atomic_store((unsigned int*)hbd + (1-p)*8192 + gb*256 + wg*2 + up, pk,
                         __ATOMIC_RELAXED, __HIP_MEMORY_SCOPE_AGENT);
      *((unsigned int*)hs + (size_t)(gb*TT + t)*256 + wg*2 + up) = pk;  // seq output
      // prefetch xg for s+1
      int tn = (dir ? (510 - s) : (s + 1)) & 511;
      const unsigned int* xp = (const unsigned int*)xg + ((size_t)gb*TT + tn)*768;
      xz_r = xp[0*256 + wg*2 + up];
      xr_r = xp[1*256 + wg*2 + up];
      xh_r = xp[2*256 + wg*2 + up];
    }
  }
}

// ---------------- row softmax over V=1024, in place ----------------
__global__ __launch_bounds__(256) void softmax_k(float* __restrict__ p) {
  size_t row = blockIdx.x;
  float* pr = p + row*VV;
  int tid = threadIdx.x;
  float4 v = ((float4*)pr)[tid];
  float m = fmaxf(fmaxf(v.x, v.y), fmaxf(v.z, v.w));
#pragma unroll
  for (int o = 32; o >= 1; o >>= 1) m = fmaxf(m, __shfl_xor(m, o));
  __shared__ float red[4];
  __shared__ float red2[4];
  int w = tid >> 6;
  if ((tid & 63) == 0) red[w] = m;
  __syncthreads();
  m = fmaxf(fmaxf(red[0], red[1]), fmaxf(red[2], red[3]));
  v.x = __expf(v.x - m); v.y = __expf(v.y - m);
  v.z = __expf(v.z - m); v.w = __expf(v.w - m);
  float s = v.x + v.y + v.z + v.w;
#pragma unroll
  for (int o = 32; o >= 1; o >>= 1) s += __shfl_xor(s, o);
  if ((tid & 63) == 0) red2[w] = s;
  __syncthreads();
  s = red2[0] + red2[1] + red2[2] + red2[3];
  float inv = 1.f / s;
  v.x *= inv; v.y *= inv; v.z *= inv; v.w *= inv;
  ((float4*)pr)[tid] = v;
}

extern "C" void kernel_launch(void* const* d_in, const int* in_sizes, int n_in,
                              void* d_out, int out_size, void* d_ws, size_t ws_size,
                              hipStream_t stream) {
  const float* x      = (const float*)d_in[0];
  const float* conv_w = (const float*)d_in[1];
  const float* conv_b = (const float*)d_in[2];
  const float* wx_f   = (const float*)d_in[3];
  const float* wh_f   = (const float*)d_in[4];
  const float* bi_f   = (const float*)d_in[5];
  const float* br_f   = (const float*)d_in[6];
  const float* wx_b   = (const float*)d_in[7];
  const float* wh_b   = (const float*)d_in[8];
  const float* bi_b   = (const float*)d_in[9];
  const float* br_b   = (const float*)d_in[10];
  const float* gam    = (const float*)d_in[11];
  const float* bet    = (const float*)d_in[12];
  const float* mu_    = (const float*)d_in[13];
  const float* var_   = (const float*)d_in[14];
  const float* dw     = (const float*)d_in[15];
  const float* db     = (const float*)d_in[16];

  char* ws = (char*)d_ws;
  __half* c0   = (__half*)(ws + 0);                 // 16,777,216  (conv/BN out; later hs2_f)
  __half* xgf  = (__half*)(ws + 16777216LL);        // 50,331,648
  __half* xgb  = (__half*)(ws + 67108864LL);        // 50,331,648
  __half* hs1f = (__half*)(ws + 117440512LL);       // 16,777,216  (later hs2_b)
  __half* hs1b = (__half*)(ws + 134217728LL);       // 16,777,216
  unsigned short* hb = (unsigned short*)(ws + 150994944LL);  // 131,072 (f16 ping-pong)
  unsigned int* flags = (unsigned int*)(ws + 151126016LL);   // 1,024 (2 layers x 2 dirs x 4 stripes x 64B)
  if (ws_size < 151128064ULL) return;
  __half* hs2f = c0;
  __half* hs2b = hs1f;
  float* logits = (float*)d_out;

  hipMemsetAsync(flags, 0, 1024, stream);

  dim3 cg(32, 32, 2);
  conv_bn_k<<<cg, 256, 0, stream>>>(x, conv_w, conv_b, gam, bet, mu_, var_, c0);

  dim3 g1(12, 128);  // N/128, M/128 for N=1536
  sgemm_k<0,1><<<g1, 256, 0, stream>>>(c0, nullptr, nullptr,nullptr,nullptr,nullptr,
                                       wx_f, bi_f, xgf, MM, GG, CC);
  sgemm_k<0,1><<<g1, 256, 0, stream>>>(c0, nullptr, nullptr,nullptr,nullptr,nullptr,
                                       wx_b, bi_b, xgb, MM, GG, CC);
  gru_layer_k<<<256, 256, 0, stream>>>(xgf, xgb, wh_f, wh_b, br_f, br_b,
                                       hs1f, hs1b, hb, flags);
  sgemm_k<1,1><<<g1, 256, 0, stream>>>(hs1f, hs1b, nullptr,nullptr,nullptr,nullptr,
                                       wx_f, bi_f, xgf, MM, GG, CC);
  sgemm_k<1,1><<<g1, 256, 0, stream>>>(hs1f, hs1b, nullptr,nullptr,nullptr,nullptr,
                                       wx_b, bi_b, xgb, MM, GG, CC);
  gru_layer_k<<<256, 256, 0, stream>>>(xgf, xgb, wh_f, wh_b, br_f, br_b,
                                       hs2f, hs2b, hb, flags + 128);
  dim3 g2(8, 128);   // N=1024
  sgemm_k<2,0><<<g2, 256, 0, stream>>>(hs2f, hs2b, gam, bet, mu_, var_,
                                       dw, db, logits, MM, VV, CC);
  softmax_k<<<MM, 256, 0, stream>>>(logits);
}

// Round 5
// 4202.528 us; speedup vs baseline: 2.5918x; 1.7102x over previous
//
#include <hip/hip_runtime.h>
#include <hip/hip_fp16.h>

#define BB 32
#define CC 512
#define UU 512
#define GG 1536
#define VV 1024
#define TT 512
#define MM (BB*TT)   // 16384
#define TIN 1024
#define FIN 80
#define EPS 1e-3f

typedef _Float16 f16x2 __attribute__((ext_vector_type(2)));
typedef _Float16 h8 __attribute__((ext_vector_type(8)));
typedef float f4 __attribute__((ext_vector_type(4)));

__device__ __forceinline__ f16x2 asf16x2(unsigned u) {
  union { unsigned u; f16x2 h; } v; v.u = u; return v.h;
}
__device__ __forceinline__ float fdot2_(f16x2 a, f16x2 b, float c) {
#if __has_builtin(__builtin_amdgcn_fdot2)
  return __builtin_amdgcn_fdot2(a, b, c, false);
#else
  return c + (float)a[0]*(float)b[0] + (float)a[1]*(float)b[1];
#endif
}

// ---------------- conv1d(stride2,SAME) + bias + relu + BN -> f16 ----------------
__global__ __launch_bounds__(256) void conv_bn_k(
    const float* __restrict__ x, const float* __restrict__ w, const float* __restrict__ cb,
    const float* __restrict__ gam, const float* __restrict__ bet,
    const float* __restrict__ mu_, const float* __restrict__ var_,
    __half* __restrict__ out)
{
  __shared__ float xs[41*80];
  int tg = blockIdx.x, b = blockIdx.y, ch = blockIdx.z;
  int t0 = tg*16;
  int in0 = t0*2 - 4;
  for (int i = threadIdx.x; i < 41*80; i += 256) {
    int r = i / 80, f = i - r*80;
    int ri = in0 + r;
    xs[i] = (ri >= 0 && ri < TIN) ? x[((size_t)b*TIN + ri)*FIN + f] : 0.f;
  }
  __syncthreads();
  int c = ch*256 + threadIdx.x;
  float acc[16];
  float bv = cb[c];
#pragma unroll
  for (int i = 0; i < 16; i++) acc[i] = bv;
  for (int k = 0; k < 11; k++) {
    for (int f = 0; f < 80; f++) {
      float wv = w[((size_t)k*80 + f)*CC + c];
#pragma unroll
      for (int i = 0; i < 16; i++) acc[i] += xs[(2*i + k)*80 + f] * wv;
    }
  }
  float ga = gam[c], be = bet[c], mu = mu_[c], iv = rsqrtf(var_[c] + EPS);
#pragma unroll
  for (int i = 0; i < 16; i++) {
    float v = fmaxf(acc[i], 0.f);
    out[((size_t)b*TT + t0 + i)*CC + c] = __float2half(ga*(v - mu)*iv + be);
  }
}

// -------- prep: transpose+cvt Wx (512x1536 f32) -> WxT2 (1536 x 1024 f16, k dup) --------
__global__ __launch_bounds__(256) void prep_wx_k(
    const float* __restrict__ wxf, const float* __restrict__ wxb,
    __half* __restrict__ of, __half* __restrict__ ob)
{
  __shared__ float tile[64][65];
  int kt = blockIdx.x*64, nt = blockIdx.y*64;
  const float* src = blockIdx.z ? wxb : wxf;
  __half* dst = blockIdx.z ? ob : of;
  for (int i = threadIdx.x; i < 4096; i += 256) {
    int r = i >> 6, c = i & 63;
    tile[r][c] = src[(size_t)(kt+r)*GG + nt + c];
  }
  __syncthreads();
  for (int i = threadIdx.x; i < 4096; i += 256) {
    int r = i >> 6, c = i & 63;          // r = n, c = k
    __half h = __float2half(tile[c][r]);
    dst[(size_t)(nt+r)*1024 + kt + c] = h;
    dst[(size_t)(nt+r)*1024 + 512 + kt + c] = h;
  }
}

// -------- prep: dense_w (512x1024) scaled by BN gamma*rsqrt -> DwT2 (1024x1024 f16, dup) --------
__global__ __launch_bounds__(256) void prep_dense_k(
    const float* __restrict__ dw, const float* __restrict__ gam, const float* __restrict__ var_,
    __half* __restrict__ dst)
{
  __shared__ float tile[64][65];
  __shared__ float s64[64];
  int kt = blockIdx.x*64, nt = blockIdx.y*64;
  if (threadIdx.x < 64) {
    int k = kt + threadIdx.x;
    s64[threadIdx.x] = gam[k] * rsqrtf(var_[k] + EPS);
  }
  for (int i = threadIdx.x; i < 4096; i += 256) {
    int r = i >> 6, c = i & 63;
    tile[r][c] = dw[(size_t)(kt+r)*VV + nt + c];
  }
  __syncthreads();
  for (int i = threadIdx.x; i < 4096; i += 256) {
    int r = i >> 6, c = i & 63;          // r = n, c = k
    __half h = __float2half(tile[c][r] * s64[c]);
    dst[(size_t)(nt+r)*1024 + kt + c] = h;
    dst[(size_t)(nt+r)*1024 + 512 + kt + c] = h;
  }
}

// -------- prep: bias2[n] = db[n] + sum_k (bet - gam*mu*rs)[k] * dw[k][n] --------
__global__ __launch_bounds__(256) void prep_bias_k(
    const float* __restrict__ dw, const float* __restrict__ db,
    const float* __restrict__ gam, const float* __restrict__ bet,
    const float* __restrict__ mu_, const float* __restrict__ var_,
    float* __restrict__ bias2)
{
  int n = blockIdx.x*256 + threadIdx.x;
  float acc = db[n];
  for (int k = 0; k < CC; k++) {
    float o = bet[k] - gam[k]*mu_[k]*rsqrtf(var_[k] + EPS);
    acc += o * dw[(size_t)k*VV + n];
  }
  bias2[n] = acc;
}

// ---------------- f16 MFMA GEMM: C[M,N] = A[M,K](f16,lda) @ BT[N,K]^T(f16,ldb) + bias ----------------
template<int OUTH>
__global__ __launch_bounds__(256,2) void hgemm_k(
    const __half* __restrict__ A, const __half* __restrict__ BT,
    const float* __restrict__ bias, void* __restrict__ Cout,
    int M, int N, int K, int lda, int ldb)
{
  __shared__ _Float16 As[128*40];
  __shared__ _Float16 Bs[128*40];
  int m0 = blockIdx.y*128, n0 = blockIdx.x*128;
  int tid = threadIdx.x;
  int l = tid & 63, w = tid >> 6;
  int wr = w >> 1, wc = w & 1;
  int srow = tid >> 1, soff = (tid & 1)*16;
  const __half* ap = A  + (size_t)(m0 + srow)*lda + soff;
  const __half* bp = BT + (size_t)(n0 + srow)*ldb + soff;
  f4 acc[4][4];
#pragma unroll
  for (int i=0;i<4;i++)
#pragma unroll
    for (int j=0;j<4;j++) acc[i][j] = (f4){0.f,0.f,0.f,0.f};

  uint4 av  = *(const uint4*)(ap);
  uint4 av2 = *(const uint4*)(ap + 8);
  uint4 bv  = *(const uint4*)(bp);
  uint4 bv2 = *(const uint4*)(bp + 8);
  int lr = (l & 15), lk = (l >> 4)*8;
  for (int k0 = 0; k0 < K; k0 += 32) {
    __syncthreads();
    *(uint4*)&As[srow*40 + soff]     = av;
    *(uint4*)&As[srow*40 + soff + 8] = av2;
    *(uint4*)&Bs[srow*40 + soff]     = bv;
    *(uint4*)&Bs[srow*40 + soff + 8] = bv2;
    __syncthreads();
    if (k0 + 32 < K) {
      av  = *(const uint4*)(ap + k0 + 32);
      av2 = *(const uint4*)(ap + k0 + 40);
      bv  = *(const uint4*)(bp + k0 + 32);
      bv2 = *(const uint4*)(bp + k0 + 40);
    }
    h8 af[4], bf[4];
#pragma unroll
    for (int i = 0; i < 4; i++)
      af[i] = *(const h8*)&As[(wr*64 + i*16 + lr)*40 + lk];
#pragma unroll
    for (int j = 0; j < 4; j++)
      bf[j] = *(const h8*)&Bs[(wc*64 + j*16 + lr)*40 + lk];
#pragma unroll
    for (int i = 0; i < 4; i++)
#pragma unroll
      for (int j = 0; j < 4; j++)
        acc[i][j] = __builtin_amdgcn_mfma_f32_16x16x32_f16(af[i], bf[j], acc[i][j], 0, 0, 0);
  }
  int cb = n0 + wc*64 + lr;
  int rb = m0 + wr*64 + (l >> 4)*4;
#pragma unroll
  for (int j = 0; j < 4; j++) {
    float bs = bias[cb + j*16];
#pragma unroll
    for (int i = 0; i < 4; i++) {
#pragma unroll
      for (int q = 0; q < 4; q++) {
        float v = acc[i][j][q] + bs;
        int row = rb + i*16 + q, col = cb + j*16;
        if (OUTH) ((__half*)Cout)[(size_t)row*N + col] = __float2half(v);
        else      ((float*)Cout)[(size_t)row*N + col] = v;
      }
    }
  }
}

// ---------------- persistent bidirectional GRU layer ----------------
// 256 WGs = 2 dir x 4 batch-groups x 32 WGs. WG: 8 batches x 16 u.
// Sync only within the 32-WG group: store-flag arrival + 32-lane relaxed poll.
__global__ __launch_bounds__(256,1) void gru_layer_k(
    const __half* __restrict__ xgf, const __half* __restrict__ xgb,
    const float* __restrict__ whf, const float* __restrict__ whb,
    const float* __restrict__ brf, const float* __restrict__ brb,
    __half* __restrict__ H,           // [16384][1024], cols dir*512+u
    unsigned short* __restrict__ hb, unsigned int* __restrict__ flags)
{
  int wg  = blockIdx.x & 31;
  int bg  = (blockIdx.x >> 5) & 3;
  int dir = blockIdx.x >> 7;
  const __half* xg = dir ? xgb : xgf;
  const float* wh  = dir ? whb : whf;
  const float* brc = dir ? brb : brf;
  unsigned short* hbd = hb + (size_t)dir * 32768;      // [2][32][512] f16
  unsigned int* flg = flags + (dir*4 + bg)*64;         // 32 used, 256B region
  int tid = threadIdx.x;
  int u0 = wg*16, b0 = bg*8;

  __shared__ _Float16 hsl[8*512];
  __shared__ float S[16*48*9];

  int kh = tid >> 4, uu = tid & 15;
  unsigned wpk[3][16];
#pragma unroll
  for (int c = 0; c < 3; c++) {
    int col = c*512 + u0 + uu;
#pragma unroll
    for (int i = 0; i < 16; i++) {
      int k = kh*32 + 2*i;
      __half2 h2 = __floats2half2_rn(wh[(size_t)k*GG + col], wh[(size_t)(k+1)*GG + col]);
      wpk[c][i] = *(unsigned*)&h2;
    }
  }

  int gb_ = tid >> 3, up = tid & 7;
  float br3[3][2];
  float hreg[2] = {0.f, 0.f};
  unsigned xz_r = 0, xr_r = 0, xh_r = 0;
  if (tid < 64) {
    int u = u0 + up*2;
#pragma unroll
    for (int g = 0; g < 3; g++) { br3[g][0] = brc[g*512+u]; br3[g][1] = brc[g*512+u+1]; }
    __hip_atomic_store((unsigned*)hbd + (b0+gb_)*256 + (u0>>1) + up, 0u,
                       __ATOMIC_RELAXED, __HIP_MEMORY_SCOPE_AGENT);
    int t0_ = dir ? 511 : 0;
    const unsigned* xp = (const unsigned*)xg + (size_t)((b0+gb_)*TT + t0_)*768;
    xz_r = xp[0*256 + (u0>>1) + up];
    xr_r = xp[1*256 + (u0>>1) + up];
    xh_r = xp[2*256 + (u0>>1) + up];
  }

  for (int s = 0; s < 512; s++) {
    __syncthreads();   // drains vmcnt(0): publish stores at coherence point
    if (tid < 32) {
      unsigned tgt = (unsigned)(s + 1);
      if (tid == 0)
        __hip_atomic_store(&flg[wg], tgt, __ATOMIC_RELAXED, __HIP_MEMORY_SCOPE_AGENT);
      long guard = 0;
      for (;;) {
        unsigned v = __hip_atomic_load(&flg[tid], __ATOMIC_RELAXED, __HIP_MEMORY_SCOPE_AGENT);
        if (__all(v >= tgt)) break;
        if (++guard > 2000000L) break;   // bailout: wrong answer, no hang
        __builtin_amdgcn_s_sleep(2);
      }
    }
    __syncthreads();
    int p = s & 1;
    {
      const unsigned short* gp = hbd + p*16384 + b0*512 + tid*16;
      float4 t0, t1;
      asm volatile(
        "global_load_dwordx4 %0, %2, off sc0 sc1\n\t"
        "global_load_dwordx4 %1, %2, off offset:16 sc0 sc1\n\t"
        "s_waitcnt vmcnt(0)"
        : "=&v"(t0), "=&v"(t1) : "v"(gp) : "memory");
      *(float4*)&hsl[tid*16]     = t0;
      *(float4*)&hsl[tid*16 + 8] = t1;
    }
    __syncthreads();
    float acc[3][8];
#pragma unroll
    for (int c = 0; c < 3; c++)
#pragma unroll
      for (int r = 0; r < 8; r++) acc[c][r] = 0.f;
#pragma unroll
    for (int k8 = 0; k8 < 4; k8++) {
      uint4 hv[8];
#pragma unroll
      for (int r = 0; r < 8; r++)
        hv[r] = *(const uint4*)&hsl[r*512 + kh*32 + k8*8];
#pragma unroll
      for (int r = 0; r < 8; r++) {
        f16x2 h0 = asf16x2(hv[r].x), h1 = asf16x2(hv[r].y);
        f16x2 h2 = asf16x2(hv[r].z), h3 = asf16x2(hv[r].w);
#pragma unroll
        for (int c = 0; c < 3; c++) {
          float a = acc[c][r];
          a = fdot2_(h0, asf16x2(wpk[c][k8*4+0]), a);
          a = fdot2_(h1, asf16x2(wpk[c][k8*4+1]), a);
          a = fdot2_(h2, asf16x2(wpk[c][k8*4+2]), a);
          a = fdot2_(h3, asf16x2(wpk[c][k8*4+3]), a);
          acc[c][r] = a;
        }
      }
    }
#pragma unroll
    for (int c = 0; c < 3; c++)
#pragma unroll
      for (int r = 0; r < 8; r++)
        S[(kh*48 + c*16 + uu)*9 + r] = acc[c][r];
    __syncthreads();
    if (tid < 64) {
      int t = dir ? (511 - s) : s;
      float rg[3][2] = {{br3[0][0],br3[0][1]},{br3[1][0],br3[1][1]},{br3[2][0],br3[2][1]}};
#pragma unroll
      for (int q = 0; q < 16; q++)
#pragma unroll
        for (int g = 0; g < 3; g++) {
          rg[g][0] += S[(q*48 + g*16 + up*2 + 0)*9 + gb_];
          rg[g][1] += S[(q*48 + g*16 + up*2 + 1)*9 + gb_];
        }
      __half2 xzh = *(__half2*)&xz_r, xrh = *(__half2*)&xr_r, xhh = *(__half2*)&xh_r;
      float2 xzv = __half22float2(xzh), xrv = __half22float2(xrh), xhv = __half22float2(xhh);
      float xzf[2] = {xzv.x, xzv.y}, xrf[2] = {xrv.x, xrv.y}, xhf[2] = {xhv.x, xhv.y};
#pragma unroll
      for (int e = 0; e < 2; e++) {
        float z = 1.f/(1.f + __expf(-(xzf[e] + rg[0][e])));
        float r = 1.f/(1.f + __expf(-(xrf[e] + rg[1][e])));
        float hh = fmaxf(xhf[e] + r*rg[2][e], 0.f);
        hreg[e] = z*hreg[e] + (1.f - z)*hh;
      }
      __half2 hp2 = __floats2half2_rn(hreg[0], hreg[1]);
      unsigned pk = *(unsigned*)&hp2;
      __hip_atomic_store((unsigned*)hbd + (1-p)*8192 + (b0+gb_)*256 + (u0>>1) + up, pk,
                         __ATOMIC_RELAXED, __HIP_MEMORY_SCOPE_AGENT);
      int row = (b0+gb_)*TT + t;
      ((unsigned*)H)[(size_t)row*512 + dir*256 + (u0>>1) + up] = pk;
      int tn = (dir ? (510 - s) : (s + 1)) & 511;
      const unsigned* xp = (const unsigned*)xg + (size_t)((b0+gb_)*TT + tn)*768;
      xz_r = xp[0*256 + (u0>>1) + up];
      xr_r = xp[1*256 + (u0>>1) + up];
      xh_r = xp[2*256 + (u0>>1) + up];
    }
  }
}

// ---------------- row softmax over V=1024, in place ----------------
__global__ __launch_bounds__(256) void softmax_k(float* __restrict__ p) {
  size_t row = blockIdx.x;
  float* pr = p + row*VV;
  int tid = threadIdx.x;
  float4 v = ((float4*)pr)[tid];
  float m = fmaxf(fmaxf(v.x, v.y), fmaxf(v.z, v.w));
#pragma unroll
  for (int o = 32; o >= 1; o >>= 1) m = fmaxf(m, __shfl_xor(m, o));
  __shared__ float red[4];
  __shared__ float red2[4];
  int w = tid >> 6;
  if ((tid & 63) == 0) red[w] = m;
  __syncthreads();
  m = fmaxf(fmaxf(red[0], red[1]), fmaxf(red[2], red[3]));
  v.x = __expf(v.x - m); v.y = __expf(v.y - m);
  v.z = __expf(v.z - m); v.w = __expf(v.w - m);
  float s = v.x + v.y + v.z + v.w;
#pragma unroll
  for (int o = 32; o >= 1; o >>= 1) s += __shfl_xor(s, o);
  if ((tid & 63) == 0) red2[w] = s;
  __syncthreads();
  s = red2[0] + red2[1] + red2[2] + red2[3];
  float inv = 1.f / s;
  v.x *= inv; v.y *= inv; v.z *= inv; v.w *= inv;
  ((float4*)pr)[tid] = v;
}

extern "C" void kernel_launch(void* const* d_in, const int* in_sizes, int n_in,
                              void* d_out, int out_size, void* d_ws, size_t ws_size,
                              hipStream_t stream) {
  const float* x      = (const float*)d_in[0];
  const float* conv_w = (const float*)d_in[1];
  const float* conv_b = (const float*)d_in[2];
  const float* wx_f   = (const float*)d_in[3];
  const float* wh_f   = (const float*)d_in[4];
  const float* bi_f   = (const float*)d_in[5];
  const float* br_f   = (const float*)d_in[6];
  const float* wx_b   = (const float*)d_in[7];
  const float* wh_b   = (const float*)d_in[8];
  const float* bi_b   = (const float*)d_in[9];
  const float* br_b   = (const float*)d_in[10];
  const float* gam    = (const float*)d_in[11];
  const float* bet    = (const float*)d_in[12];
  const float* mu_    = (const float*)d_in[13];
  const float* var_   = (const float*)d_in[14];
  const float* dw     = (const float*)d_in[15];
  const float* db     = (const float*)d_in[16];

  char* ws = (char*)d_ws;
  __half* xgf   = (__half*)(ws + 0);
  __half* xgb   = (__half*)(ws + 50331648LL);
  __half* WxfT2 = (__half*)(ws + 100663296LL);
  __half* WxbT2 = (__half*)(ws + 103809024LL);
  __half* DwT2  = (__half*)(ws + 106954752LL);
  float*  bias2 = (float*)(ws + 109051904LL);
  __half* c0    = (__half*)(ws + 109056000LL);
  __half* H     = (__half*)(ws + 109056000LL);   // overlays c0 (c0 dead before H written)
  unsigned short* hb = (unsigned short*)(ws + 142610432LL);
  unsigned int* flags = (unsigned int*)(ws + 142741504LL);
  if (ws_size < 151257152ULL) return;
  float* logits = (float*)d_out;

  hipMemsetAsync(flags, 0, 4096, stream);

  prep_wx_k<<<dim3(8,24,2), 256, 0, stream>>>(wx_f, wx_b, WxfT2, WxbT2);
  prep_dense_k<<<dim3(8,16), 256, 0, stream>>>(dw, gam, var_, DwT2);
  prep_bias_k<<<4, 256, 0, stream>>>(dw, db, gam, bet, mu_, var_, bias2);

  conv_bn_k<<<dim3(32,32,2), 256, 0, stream>>>(x, conv_w, conv_b, gam, bet, mu_, var_, c0);

  hgemm_k<1><<<dim3(12,128), 256, 0, stream>>>(c0, WxfT2, bi_f, xgf, MM, GG, 512, 512, 1024);
  hgemm_k<1><<<dim3(12,128), 256, 0, stream>>>(c0, WxbT2, bi_b, xgb, MM, GG, 512, 512, 1024);
  gru_layer_k<<<256, 256, 0, stream>>>(xgf, xgb, wh_f, wh_b, br_f, br_b, H, hb, flags);
  hgemm_k<1><<<dim3(12,128), 256, 0, stream>>>(H, WxfT2, bi_f, xgf, MM, GG, 1024, 1024, 1024);
  hgemm_k<1><<<dim3(12,128), 256, 0, stream>>>(H, WxbT2, bi_b, xgb, MM, GG, 1024, 1024, 1024);
  gru_layer_k<<<256, 256, 0, stream>>>(xgf, xgb, wh_f, wh_b, br_f, br_b, H, hb, flags + 512);
  hgemm_k<0><<<dim3(8,128), 256, 0, stream>>>(H, DwT2, bias2, logits, MM, VV, 1024, 1024, 1024);
  softmax_k<<<MM, 256, 0, stream>>>(logits);
}

// Round 6
// 3767.734 us; speedup vs baseline: 2.8908x; 1.1154x over previous
//
#include <hip/hip_runtime.h>
#include <hip/hip_fp16.h>

#define BB 32
#define CC 512
#define UU 512
#define GG 1536
#define VV 1024
#define TT 512
#define MM (BB*TT)   // 16384
#define TIN 1024
#define FIN 80
#define EPS 1e-3f

typedef _Float16 f16x2 __attribute__((ext_vector_type(2)));
typedef _Float16 h8 __attribute__((ext_vector_type(8)));
typedef float f4 __attribute__((ext_vector_type(4)));

__device__ __forceinline__ f16x2 asf16x2(unsigned u) {
  union { unsigned u; f16x2 h; } v; v.u = u; return v.h;
}
__device__ __forceinline__ float fdot2_(f16x2 a, f16x2 b, float c) {
#if __has_builtin(__builtin_amdgcn_fdot2)
  return __builtin_amdgcn_fdot2(a, b, c, false);
#else
  return c + (float)a[0]*(float)b[0] + (float)a[1]*(float)b[1];
#endif
}

// ---------------- conv1d(stride2,SAME) + bias + relu + BN -> f16 ----------------
__global__ __launch_bounds__(256) void conv_bn_k(
    const float* __restrict__ x, const float* __restrict__ w, const float* __restrict__ cb,
    const float* __restrict__ gam, const float* __restrict__ bet,
    const float* __restrict__ mu_, const float* __restrict__ var_,
    __half* __restrict__ out)
{
  __shared__ float xs[41*80];
  int tg = blockIdx.x, b = blockIdx.y, ch = blockIdx.z;
  int t0 = tg*16;
  int in0 = t0*2 - 4;
  for (int i = threadIdx.x; i < 41*80; i += 256) {
    int r = i / 80, f = i - r*80;
    int ri = in0 + r;
    xs[i] = (ri >= 0 && ri < TIN) ? x[((size_t)b*TIN + ri)*FIN + f] : 0.f;
  }
  __syncthreads();
  int c = ch*256 + threadIdx.x;
  float acc[16];
  float bv = cb[c];
#pragma unroll
  for (int i = 0; i < 16; i++) acc[i] = bv;
  for (int k = 0; k < 11; k++) {
    for (int f = 0; f < 80; f++) {
      float wv = w[((size_t)k*80 + f)*CC + c];
#pragma unroll
      for (int i = 0; i < 16; i++) acc[i] += xs[(2*i + k)*80 + f] * wv;
    }
  }
  float ga = gam[c], be = bet[c], mu = mu_[c], iv = rsqrtf(var_[c] + EPS);
#pragma unroll
  for (int i = 0; i < 16; i++) {
    float v = fmaxf(acc[i], 0.f);
    out[((size_t)b*TT + t0 + i)*CC + c] = __float2half(ga*(v - mu)*iv + be);
  }
}

// -------- prep: transpose+cvt Wx (512x1536 f32) -> WxT2 (1536 x 1024 f16, k dup) --------
__global__ __launch_bounds__(256) void prep_wx_k(
    const float* __restrict__ wxf, const float* __restrict__ wxb,
    __half* __restrict__ of, __half* __restrict__ ob)
{
  __shared__ float tile[64][65];
  int kt = blockIdx.x*64, nt = blockIdx.y*64;
  const float* src = blockIdx.z ? wxb : wxf;
  __half* dst = blockIdx.z ? ob : of;
  for (int i = threadIdx.x; i < 4096; i += 256) {
    int r = i >> 6, c = i & 63;
    tile[r][c] = src[(size_t)(kt+r)*GG + nt + c];
  }
  __syncthreads();
  for (int i = threadIdx.x; i < 4096; i += 256) {
    int r = i >> 6, c = i & 63;          // r = n, c = k
    __half h = __float2half(tile[c][r]);
    dst[(size_t)(nt+r)*1024 + kt + c] = h;
    dst[(size_t)(nt+r)*1024 + 512 + kt + c] = h;
  }
}

// -------- prep: dense_w (512x1024) scaled by BN gamma*rsqrt -> DwT2 (1024x1024 f16, dup) --------
__global__ __launch_bounds__(256) void prep_dense_k(
    const float* __restrict__ dw, const float* __restrict__ gam, const float* __restrict__ var_,
    __half* __restrict__ dst)
{
  __shared__ float tile[64][65];
  __shared__ float s64[64];
  int kt = blockIdx.x*64, nt = blockIdx.y*64;
  if (threadIdx.x < 64) {
    int k = kt + threadIdx.x;
    s64[threadIdx.x] = gam[k] * rsqrtf(var_[k] + EPS);
  }
  for (int i = threadIdx.x; i < 4096; i += 256) {
    int r = i >> 6, c = i & 63;
    tile[r][c] = dw[(size_t)(kt+r)*VV + nt + c];
  }
  __syncthreads();
  for (int i = threadIdx.x; i < 4096; i += 256) {
    int r = i >> 6, c = i & 63;          // r = n, c = k
    __half h = __float2half(tile[c][r] * s64[c]);
    dst[(size_t)(nt+r)*1024 + kt + c] = h;
    dst[(size_t)(nt+r)*1024 + 512 + kt + c] = h;
  }
}

// -------- prep: bias2[n] = db[n] + sum_k (bet - gam*mu*rs)[k] * dw[k][n] --------
__global__ __launch_bounds__(256) void prep_bias_k(
    const float* __restrict__ dw, const float* __restrict__ db,
    const float* __restrict__ gam, const float* __restrict__ bet,
    const float* __restrict__ mu_, const float* __restrict__ var_,
    float* __restrict__ bias2)
{
  int n = blockIdx.x*256 + threadIdx.x;
  float acc = db[n];
  for (int k = 0; k < CC; k++) {
    float o = bet[k] - gam[k]*mu_[k]*rsqrtf(var_[k] + EPS);
    acc += o * dw[(size_t)k*VV + n];
  }
  bias2[n] = acc;
}

// ---------------- f16 MFMA GEMM: C[M,N] = A[M,K](f16,lda) @ BT[N,K]^T(f16,ldb) + bias ----------------
template<int OUTH>
__global__ __launch_bounds__(256,2) void hgemm_k(
    const __half* __restrict__ A, const __half* __restrict__ BT,
    const float* __restrict__ bias, void* __restrict__ Cout,
    int M, int N, int K, int lda, int ldb)
{
  __shared__ _Float16 As[128*40];
  __shared__ _Float16 Bs[128*40];
  int m0 = blockIdx.y*128, n0 = blockIdx.x*128;
  int tid = threadIdx.x;
  int l = tid & 63, w = tid >> 6;
  int wr = w >> 1, wc = w & 1;
  int srow = tid >> 1, soff = (tid & 1)*16;
  const __half* ap = A  + (size_t)(m0 + srow)*lda + soff;
  const __half* bp = BT + (size_t)(n0 + srow)*ldb + soff;
  f4 acc[4][4];
#pragma unroll
  for (int i=0;i<4;i++)
#pragma unroll
    for (int j=0;j<4;j++) acc[i][j] = (f4){0.f,0.f,0.f,0.f};

  uint4 av  = *(const uint4*)(ap);
  uint4 av2 = *(const uint4*)(ap + 8);
  uint4 bv  = *(const uint4*)(bp);
  uint4 bv2 = *(const uint4*)(bp + 8);
  int lr = (l & 15), lk = (l >> 4)*8;
  for (int k0 = 0; k0 < K; k0 += 32) {
    __syncthreads();
    *(uint4*)&As[srow*40 + soff]     = av;
    *(uint4*)&As[srow*40 + soff + 8] = av2;
    *(uint4*)&Bs[srow*40 + soff]     = bv;
    *(uint4*)&Bs[srow*40 + soff + 8] = bv2;
    __syncthreads();
    if (k0 + 32 < K) {
      av  = *(const uint4*)(ap + k0 + 32);
      av2 = *(const uint4*)(ap + k0 + 40);
      bv  = *(const uint4*)(bp + k0 + 32);
      bv2 = *(const uint4*)(bp + k0 + 40);
    }
    h8 af[4], bf[4];
#pragma unroll
    for (int i = 0; i < 4; i++)
      af[i] = *(const h8*)&As[(wr*64 + i*16 + lr)*40 + lk];
#pragma unroll
    for (int j = 0; j < 4; j++)
      bf[j] = *(const h8*)&Bs[(wc*64 + j*16 + lr)*40 + lk];
#pragma unroll
    for (int i = 0; i < 4; i++)
#pragma unroll
      for (int j = 0; j < 4; j++)
        acc[i][j] = __builtin_amdgcn_mfma_f32_16x16x32_f16(af[i], bf[j], acc[i][j], 0, 0, 0);
  }
  int cb = n0 + wc*64 + lr;
  int rb = m0 + wr*64 + (l >> 4)*4;
#pragma unroll
  for (int j = 0; j < 4; j++) {
    float bs = bias[cb + j*16];
#pragma unroll
    for (int i = 0; i < 4; i++) {
#pragma unroll
      for (int q = 0; q < 4; q++) {
        float v = acc[i][j][q] + bs;
        int row = rb + i*16 + q, col = cb + j*16;
        if (OUTH) ((__half*)Cout)[(size_t)row*N + col] = __float2half(v);
        else      ((float*)Cout)[(size_t)row*N + col] = v;
      }
    }
  }
}

// ---------------- persistent bidirectional GRU layer ----------------
// 256 WGs = 2 dir x 4 batch-groups x 32 WGs. WG: 8 batches x 16 u.
// h exchange: producer-contiguous 256B regions [8 rows][16 u] f16 with a
// per-region epoch word. Consumers hot-spin on ONLY their region's epoch,
// then load+stage that region immediately (per-producer pipelining; the
// WG-wide AND is the __syncthreads after staging). All h stores/loads sc0sc1.
__global__ __launch_bounds__(256,1) void gru_layer_k(
    const __half* __restrict__ xgf, const __half* __restrict__ xgb,
    const float* __restrict__ whf, const float* __restrict__ whb,
    const float* __restrict__ brf, const float* __restrict__ brb,
    __half* __restrict__ H,           // [16384][1024], cols dir*512+u
    unsigned short* __restrict__ hb,  // regions: [grp][2 phases][32 wg][256B]
    unsigned int* __restrict__ ep)    // epochs:  [grp][2 phases][32 wg] u32
{
  int wg  = blockIdx.x & 31;
  int bg  = (blockIdx.x >> 5) & 3;
  int dir = blockIdx.x >> 7;
  int grp = dir*4 + bg;
  const __half* xg = dir ? xgb : xgf;
  const float* wh  = dir ? whb : whf;
  const float* brc = dir ? brb : brf;
  unsigned* hbg = (unsigned*)((char*)hb + (size_t)grp*16384);  // 2*32*256B
  unsigned* epg = ep + grp*64;                                  // 2*32 u32
  int tid = threadIdx.x;
  int u0 = wg*16, b0 = bg*8;

  __shared__ _Float16 hsl[8*512];      // granule-swizzled: phys g = g ^ row
  __shared__ float S[16*48*9];         // k-partials [kh][col][r pad 9]
  __shared__ float R[48*9];            // reduced [col][r pad 9]

  // Wh slice -> packed f16 regs: thread (kh=tid>>4, uu=tid&15): 3 cols x 32 k
  int kh = tid >> 4, uu = tid & 15;
  unsigned wpk[3][16];
#pragma unroll
  for (int c = 0; c < 3; c++) {
    int col = c*512 + u0 + uu;
#pragma unroll
    for (int i = 0; i < 16; i++) {
      int k = kh*32 + 2*i;
      __half2 h2 = __floats2half2_rn(wh[(size_t)k*GG + col], wh[(size_t)(k+1)*GG + col]);
      wpk[c][i] = *(unsigned*)&h2;
    }
  }

  // gate mapping (tid<64): gb_=tid>>3 (batch), up=tid&7 (u pair)
  int gb_ = tid >> 3, up = tid & 7;
  float br3[3][2];
  float hreg[2] = {0.f, 0.f};
  unsigned xz_r = 0, xr_r = 0, xh_r = 0;
  if (tid < 64) {
    int u = u0 + up*2;
#pragma unroll
    for (int g = 0; g < 3; g++) { br3[g][0] = brc[g*512+u]; br3[g][1] = brc[g*512+u+1]; }
    // publish h0 = 0 into phase-0 region[wg] (contiguous: offset tid*4B)
    __hip_atomic_store(&hbg[(0*32 + wg)*64 + tid], 0u,
                       __ATOMIC_RELAXED, __HIP_MEMORY_SCOPE_AGENT);
    int t0_ = dir ? 511 : 0;
    const unsigned* xp = (const unsigned*)xg + (size_t)((b0+gb_)*TT + t0_)*768;
    xz_r = xp[0*256 + (u0>>1) + up];
    xr_r = xp[1*256 + (u0>>1) + up];
    xh_r = xp[2*256 + (u0>>1) + up];
  }
  __syncthreads();   // drain vmcnt(0): h0 stores at coherence point
  if (tid == 0)
    __hip_atomic_store(&epg[0*32 + wg], 1u, __ATOMIC_RELAXED, __HIP_MEMORY_SCOPE_AGENT);

  // stage mapping: thread t: region r0 = t>>3, row c = t&7 (32B = 2 b128)
  int r0 = tid >> 3, cc = tid & 7;
  int g0 = r0*2;
  int ws0 = cc*512 + (((g0  ) ^ cc) << 3);
  int ws1 = cc*512 + (((g0+1) ^ cc) << 3);

  for (int s = 0; s < 512; s++) {
    int p = s & 1;
    // ---- per-region poll + load + stage ----
    {
      unsigned tgt = (unsigned)(s + 1);
      const unsigned* eptr = &epg[p*32 + r0];
      long guard = 0;
      while (__hip_atomic_load(eptr, __ATOMIC_RELAXED, __HIP_MEMORY_SCOPE_AGENT) < tgt) {
        if (++guard > 5000000L) break;   // bailout: wrong answer, no hang
      }
      const unsigned short* gp = (const unsigned short*)
          ((char*)hbg + ((size_t)(p*32 + r0))*256 + cc*32);
      float4 t0, t1;
      asm volatile(
        "global_load_dwordx4 %0, %2, off sc0 sc1\n\t"
        "global_load_dwordx4 %1, %2, off offset:16 sc0 sc1\n\t"
        "s_waitcnt vmcnt(0)"
        : "=&v"(t0), "=&v"(t1) : "v"(gp) : "memory");
      *(float4*)&hsl[ws0] = t0;
      *(float4*)&hsl[ws1] = t1;
    }
    __syncthreads();
    // ---- rg partial: 3 cols x 8 batches, k slice kh*32..+32 (dot2) ----
    float acc[3][8];
#pragma unroll
    for (int c = 0; c < 3; c++)
#pragma unroll
      for (int r = 0; r < 8; r++) acc[c][r] = 0.f;
#pragma unroll
    for (int k8 = 0; k8 < 4; k8++) {
      int g = kh*4 + k8;
      uint4 hv[8];
#pragma unroll
      for (int r = 0; r < 8; r++)
        hv[r] = *(const uint4*)&hsl[r*512 + ((g ^ r) << 3)];
#pragma unroll
      for (int r = 0; r < 8; r++) {
        f16x2 h0 = asf16x2(hv[r].x), h1 = asf16x2(hv[r].y);
        f16x2 h2 = asf16x2(hv[r].z), h3 = asf16x2(hv[r].w);
#pragma unroll
        for (int c = 0; c < 3; c++) {
          float a = acc[c][r];
          a = fdot2_(h0, asf16x2(wpk[c][k8*4+0]), a);
          a = fdot2_(h1, asf16x2(wpk[c][k8*4+1]), a);
          a = fdot2_(h2, asf16x2(wpk[c][k8*4+2]), a);
          a = fdot2_(h3, asf16x2(wpk[c][k8*4+3]), a);
          acc[c][r] = a;
        }
      }
    }
#pragma unroll
    for (int c = 0; c < 3; c++)
#pragma unroll
      for (int r = 0; r < 8; r++)
        S[(kh*48 + c*16 + uu)*9 + r] = acc[c][r];
    __syncthreads();
    // ---- parallel reduce over 16 kh slices: 384 cells, 192 threads x 2 ----
    if (tid < 192) {
#pragma unroll
      for (int e = 0; e < 2; e++) {
        int cell = 2*tid + e;
        int col = cell >> 3, r = cell & 7;
        float a = 0.f;
#pragma unroll
        for (int q = 0; q < 16; q++) a += S[(q*48 + col)*9 + r];
        R[col*9 + r] = a;
      }
    }
    __syncthreads();
    // ---- gates (tid<64): 1 batch x 2 u ----
    if (tid < 64) {
      int t = dir ? (511 - s) : s;
      float rg[3][2];
#pragma unroll
      for (int g = 0; g < 3; g++) {
        rg[g][0] = br3[g][0] + R[(g*16 + up*2 + 0)*9 + gb_];
        rg[g][1] = br3[g][1] + R[(g*16 + up*2 + 1)*9 + gb_];
      }
      __half2 xzh = *(__half2*)&xz_r, xrh = *(__half2*)&xr_r, xhh = *(__half2*)&xh_r;
      float2 xzv = __half22float2(xzh), xrv = __half22float2(xrh), xhv = __half22float2(xhh);
      float xzf[2] = {xzv.x, xzv.y}, xrf[2] = {xrv.x, xrv.y}, xhf[2] = {xhv.x, xhv.y};
#pragma unroll
      for (int e = 0; e < 2; e++) {
        float z = 1.f/(1.f + __expf(-(xzf[e] + rg[0][e])));
        float r = 1.f/(1.f + __expf(-(xrf[e] + rg[1][e])));
        float hh = fmaxf(xhf[e] + r*rg[2][e], 0.f);
        hreg[e] = z*hreg[e] + (1.f - z)*hh;
      }
      __half2 hp2 = __floats2half2_rn(hreg[0], hreg[1]);
      unsigned pk = *(unsigned*)&hp2;
      // publish into own region of phase 1-p (contiguous 256B burst)
      __hip_atomic_store(&hbg[((1-p)*32 + wg)*64 + tid], pk,
                         __ATOMIC_RELAXED, __HIP_MEMORY_SCOPE_AGENT);
      int row = (b0+gb_)*TT + t;
      ((unsigned*)H)[(size_t)row*512 + dir*256 + (u0>>1) + up] = pk;
      int tn = (dir ? (510 - s) : (s + 1)) & 511;
      const unsigned* xp = (const unsigned*)xg + (size_t)((b0+gb_)*TT + tn)*768;
      xz_r = xp[0*256 + (u0>>1) + up];
      xr_r = xp[1*256 + (u0>>1) + up];
      xh_r = xp[2*256 + (u0>>1) + up];
    }
    __syncthreads();   // drain vmcnt(0): publish stores at coherence point
    if (tid == 0)
      __hip_atomic_store(&epg[(1-p)*32 + wg], (unsigned)(s + 2),
                         __ATOMIC_RELAXED, __HIP_MEMORY_SCOPE_AGENT);
  }
}

// ---------------- row softmax over V=1024, in place ----------------
__global__ __launch_bounds__(256) void softmax_k(float* __restrict__ p) {
  size_t row = blockIdx.x;
  float* pr = p + row*VV;
  int tid = threadIdx.x;
  float4 v = ((float4*)pr)[tid];
  float m = fmaxf(fmaxf(v.x, v.y), fmaxf(v.z, v.w));
#pragma unroll
  for (int o = 32; o >= 1; o >>= 1) m = fmaxf(m, __shfl_xor(m, o));
  __shared__ float red[4];
  __shared__ float red2[4];
  int w = tid >> 6;
  if ((tid & 63) == 0) red[w] = m;
  __syncthreads();
  m = fmaxf(fmaxf(red[0], red[1]), fmaxf(red[2], red[3]));
  v.x = __expf(v.x - m); v.y = __expf(v.y - m);
  v.z = __expf(v.z - m); v.w = __expf(v.w - m);
  float s = v.x + v.y + v.z + v.w;
#pragma unroll
  for (int o = 32; o >= 1; o >>= 1) s += __shfl_xor(s, o);
  if ((tid & 63) == 0) red2[w] = s;
  __syncthreads();
  s = red2[0] + red2[1] + red2[2] + red2[3];
  float inv = 1.f / s;
  v.x *= inv; v.y *= inv; v.z *= inv; v.w *= inv;
  ((float4*)pr)[tid] = v;
}

extern "C" void kernel_launch(void* const* d_in, const int* in_sizes, int n_in,
                              void* d_out, int out_size, void* d_ws, size_t ws_size,
                              hipStream_t stream) {
  const float* x      = (const float*)d_in[0];
  const float* conv_w = (const float*)d_in[1];
  const float* conv_b = (const float*)d_in[2];
  const float* wx_f   = (const float*)d_in[3];
  const float* wh_f   = (const float*)d_in[4];
  const float* bi_f   = (const float*)d_in[5];
  const float* br_f   = (const float*)d_in[6];
  const float* wx_b   = (const float*)d_in[7];
  const float* wh_b   = (const float*)d_in[8];
  const float* bi_b   = (const float*)d_in[9];
  const float* br_b   = (const float*)d_in[10];
  const float* gam    = (const float*)d_in[11];
  const float* bet    = (const float*)d_in[12];
  const float* mu_    = (const float*)d_in[13];
  const float* var_   = (const float*)d_in[14];
  const float* dw     = (const float*)d_in[15];
  const float* db     = (const float*)d_in[16];

  char* ws = (char*)d_ws;
  __half* xgf   = (__half*)(ws + 0);
  __half* xgb   = (__half*)(ws + 50331648LL);
  __half* WxfT2 = (__half*)(ws + 100663296LL);
  __half* WxbT2 = (__half*)(ws + 103809024LL);
  __half* DwT2  = (__half*)(ws + 106954752LL);
  float*  bias2 = (float*)(ws + 109051904LL);
  __half* c0    = (__half*)(ws + 109056000LL);
  __half* H     = (__half*)(ws + 109056000LL);   // overlays c0 (c0 dead before H written)
  unsigned short* hb = (unsigned short*)(ws + 142610432LL);  // 128 KB regions
  unsigned int* ep   = (unsigned int*)(ws + 142741504LL);    // 4 KB epochs (2 layers)
  if (ws_size < 151257152ULL) return;
  float* logits = (float*)d_out;

  hipMemsetAsync(ep, 0, 4096, stream);

  prep_wx_k<<<dim3(8,24,2), 256, 0, stream>>>(wx_f, wx_b, WxfT2, WxbT2);
  prep_dense_k<<<dim3(8,16), 256, 0, stream>>>(dw, gam, var_, DwT2);
  prep_bias_k<<<4, 256, 0, stream>>>(dw, db, gam, bet, mu_, var_, bias2);

  conv_bn_k<<<dim3(32,32,2), 256, 0, stream>>>(x, conv_w, conv_b, gam, bet, mu_, var_, c0);

  hgemm_k<1><<<dim3(12,128), 256, 0, stream>>>(c0, WxfT2, bi_f, xgf, MM, GG, 512, 512, 1024);
  hgemm_k<1><<<dim3(12,128), 256, 0, stream>>>(c0, WxbT2, bi_b, xgb, MM, GG, 512, 512, 1024);
  gru_layer_k<<<256, 256, 0, stream>>>(xgf, xgb, wh_f, wh_b, br_f, br_b, H, hb, ep);
  hgemm_k<1><<<dim3(12,128), 256, 0, stream>>>(H, WxfT2, bi_f, xgf, MM, GG, 1024, 1024, 1024);
  hgemm_k<1><<<dim3(12,128), 256, 0, stream>>>(H, WxbT2, bi_b, xgb, MM, GG, 1024, 1024, 1024);
  gru_layer_k<<<256, 256, 0, stream>>>(xgf, xgb, wh_f, wh_b, br_f, br_b, H, hb, ep + 512);
  hgemm_k<0><<<dim3(8,128), 256, 0, stream>>>(H, DwT2, bias2, logits, MM, VV, 1024, 1024, 1024);
  softmax_k<<<MM, 256, 0, stream>>>(logits);
}

// Round 7
// 2890.228 us; speedup vs baseline: 3.7685x; 1.3036x over previous
//
#include <hip/hip_runtime.h>
#include <hip/hip_fp16.h>

#define BB 32
#define CC 512
#define UU 512
#define GG 1536
#define VV 1024
#define TT 512
#define MM (BB*TT)   // 16384
#define TIN 1024
#define FIN 80
#define EPS 1e-3f
#define SENT 0xFFFFFFFFu   // two f16 NaNs — impossible as finite GRU output

typedef _Float16 h8 __attribute__((ext_vector_type(8)));
typedef float f4 __attribute__((ext_vector_type(4)));

// ---------------- conv1d(stride2,SAME) + bias + relu + BN -> f16 ----------------
__global__ __launch_bounds__(256) void conv_bn_k(
    const float* __restrict__ x, const float* __restrict__ w, const float* __restrict__ cb,
    const float* __restrict__ gam, const float* __restrict__ bet,
    const float* __restrict__ mu_, const float* __restrict__ var_,
    __half* __restrict__ out)
{
  __shared__ float xs[41*80];
  int tg = blockIdx.x, b = blockIdx.y, ch = blockIdx.z;
  int t0 = tg*16;
  int in0 = t0*2 - 4;
  for (int i = threadIdx.x; i < 41*80; i += 256) {
    int r = i / 80, f = i - r*80;
    int ri = in0 + r;
    xs[i] = (ri >= 0 && ri < TIN) ? x[((size_t)b*TIN + ri)*FIN + f] : 0.f;
  }
  __syncthreads();
  int c = ch*256 + threadIdx.x;
  float acc[16];
  float bv = cb[c];
#pragma unroll
  for (int i = 0; i < 16; i++) acc[i] = bv;
  for (int k = 0; k < 11; k++) {
    for (int f = 0; f < 80; f++) {
      float wv = w[((size_t)k*80 + f)*CC + c];
#pragma unroll
      for (int i = 0; i < 16; i++) acc[i] += xs[(2*i + k)*80 + f] * wv;
    }
  }
  float ga = gam[c], be = bet[c], mu = mu_[c], iv = rsqrtf(var_[c] + EPS);
#pragma unroll
  for (int i = 0; i < 16; i++) {
    float v = fmaxf(acc[i], 0.f);
    out[((size_t)b*TT + t0 + i)*CC + c] = __float2half(ga*(v - mu)*iv + be);
  }
}

// -------- prep: transpose+cvt Wx (512x1536 f32) -> WxT2 (1536 x 1024 f16, k dup) --------
__global__ __launch_bounds__(256) void prep_wx_k(
    const float* __restrict__ wxf, const float* __restrict__ wxb,
    __half* __restrict__ of, __half* __restrict__ ob)
{
  __shared__ float tile[64][65];
  int kt = blockIdx.x*64, nt = blockIdx.y*64;
  const float* src = blockIdx.z ? wxb : wxf;
  __half* dst = blockIdx.z ? ob : of;
  for (int i = threadIdx.x; i < 4096; i += 256) {
    int r = i >> 6, c = i & 63;
    tile[r][c] = src[(size_t)(kt+r)*GG + nt + c];
  }
  __syncthreads();
  for (int i = threadIdx.x; i < 4096; i += 256) {
    int r = i >> 6, c = i & 63;          // r = n, c = k
    __half h = __float2half(tile[c][r]);
    dst[(size_t)(nt+r)*1024 + kt + c] = h;
    dst[(size_t)(nt+r)*1024 + 512 + kt + c] = h;
  }
}

// -------- prep: dense_w (512x1024) scaled by BN gamma*rsqrt -> DwT2 (1024x1024 f16, dup) --------
__global__ __launch_bounds__(256) void prep_dense_k(
    const float* __restrict__ dw, const float* __restrict__ gam, const float* __restrict__ var_,
    __half* __restrict__ dst)
{
  __shared__ float tile[64][65];
  __shared__ float s64[64];
  int kt = blockIdx.x*64, nt = blockIdx.y*64;
  if (threadIdx.x < 64) {
    int k = kt + threadIdx.x;
    s64[threadIdx.x] = gam[k] * rsqrtf(var_[k] + EPS);
  }
  for (int i = threadIdx.x; i < 4096; i += 256) {
    int r = i >> 6, c = i & 63;
    tile[r][c] = dw[(size_t)(kt+r)*VV + nt + c];
  }
  __syncthreads();
  for (int i = threadIdx.x; i < 4096; i += 256) {
    int r = i >> 6, c = i & 63;          // r = n, c = k
    __half h = __float2half(tile[c][r] * s64[c]);
    dst[(size_t)(nt+r)*1024 + kt + c] = h;
    dst[(size_t)(nt+r)*1024 + 512 + kt + c] = h;
  }
}

// -------- prep: bias2[n] = db[n] + sum_k (bet - gam*mu*rs)[k] * dw[k][n] --------
__global__ __launch_bounds__(256) void prep_bias_k(
    const float* __restrict__ dw, const float* __restrict__ db,
    const float* __restrict__ gam, const float* __restrict__ bet,
    const float* __restrict__ mu_, const float* __restrict__ var_,
    float* __restrict__ bias2)
{
  int n = blockIdx.x*256 + threadIdx.x;
  float acc = db[n];
  for (int k = 0; k < CC; k++) {
    float o = bet[k] - gam[k]*mu_[k]*rsqrtf(var_[k] + EPS);
    acc += o * dw[(size_t)k*VV + n];
  }
  bias2[n] = acc;
}

// ---------------- f16 MFMA GEMM: C[M,N] = A[M,K](f16,lda) @ BT[N,K]^T(f16,ldb) + bias ----------------
template<int OUTH>
__global__ __launch_bounds__(256,2) void hgemm_k(
    const __half* __restrict__ A, const __half* __restrict__ BT,
    const float* __restrict__ bias, void* __restrict__ Cout,
    int M, int N, int K, int lda, int ldb)
{
  __shared__ _Float16 As[128*40];
  __shared__ _Float16 Bs[128*40];
  int m0 = blockIdx.y*128, n0 = blockIdx.x*128;
  int tid = threadIdx.x;
  int l = tid & 63, w = tid >> 6;
  int wr = w >> 1, wc = w & 1;
  int srow = tid >> 1, soff = (tid & 1)*16;
  const __half* ap = A  + (size_t)(m0 + srow)*lda + soff;
  const __half* bp = BT + (size_t)(n0 + srow)*ldb + soff;
  f4 acc[4][4];
#pragma unroll
  for (int i=0;i<4;i++)
#pragma unroll
    for (int j=0;j<4;j++) acc[i][j] = (f4){0.f,0.f,0.f,0.f};

  uint4 av  = *(const uint4*)(ap);
  uint4 av2 = *(const uint4*)(ap + 8);
  uint4 bv  = *(const uint4*)(bp);
  uint4 bv2 = *(const uint4*)(bp + 8);
  int lr = (l & 15), lk = (l >> 4)*8;
  for (int k0 = 0; k0 < K; k0 += 32) {
    __syncthreads();
    *(uint4*)&As[srow*40 + soff]     = av;
    *(uint4*)&As[srow*40 + soff + 8] = av2;
    *(uint4*)&Bs[srow*40 + soff]     = bv;
    *(uint4*)&Bs[srow*40 + soff + 8] = bv2;
    __syncthreads();
    if (k0 + 32 < K) {
      av  = *(const uint4*)(ap + k0 + 32);
      av2 = *(const uint4*)(ap + k0 + 40);
      bv  = *(const uint4*)(bp + k0 + 32);
      bv2 = *(const uint4*)(bp + k0 + 40);
    }
    h8 af[4], bf[4];
#pragma unroll
    for (int i = 0; i < 4; i++)
      af[i] = *(const h8*)&As[(wr*64 + i*16 + lr)*40 + lk];
#pragma unroll
    for (int j = 0; j < 4; j++)
      bf[j] = *(const h8*)&Bs[(wc*64 + j*16 + lr)*40 + lk];
#pragma unroll
    for (int i = 0; i < 4; i++)
#pragma unroll
      for (int j = 0; j < 4; j++)
        acc[i][j] = __builtin_amdgcn_mfma_f32_16x16x32_f16(af[i], bf[j], acc[i][j], 0, 0, 0);
  }
  int cb = n0 + wc*64 + lr;
  int rb = m0 + wr*64 + (l >> 4)*4;
#pragma unroll
  for (int j = 0; j < 4; j++) {
    float bs = bias[cb + j*16];
#pragma unroll
    for (int i = 0; i < 4; i++) {
#pragma unroll
      for (int q = 0; q < 4; q++) {
        float v = acc[i][j][q] + bs;
        int row = rb + i*16 + q, col = cb + j*16;
        if (OUTH) ((__half*)Cout)[(size_t)row*N + col] = __float2half(v);
        else      ((float*)Cout)[(size_t)row*N + col] = v;
      }
    }
  }
}

// ---------------- persistent bidirectional GRU layer (MFMA + sentinel sync) ------
// 256 WGs = 2 dir x 4 batch-groups x 32 WGs. WG: 8 batches x 16 u.
// rg matmul via mfma_f32_16x16x32_f16: wave w owns k-chunk w*128, holds 12
// B-frags of Wh in regs; per step 4 A-frag ds_reads + 12 MFMAs + 3 S stores.
// h exchange: 4-phase rotation of 256B producer regions; empty = SENT words
// (f16 NaN pair). Consumers poll DATA directly (one L3 hop). Producer resets
// phase (s+2)&3 at M; mid-barrier vmcnt drain orders reset-before-publish.
__global__ __launch_bounds__(256,1) void gru_layer_k(
    const __half* __restrict__ xgf, const __half* __restrict__ xgb,
    const float* __restrict__ whf, const float* __restrict__ whb,
    const float* __restrict__ brf, const float* __restrict__ brb,
    __half* __restrict__ H,           // [16384][1024], cols dir*512+u
    unsigned* __restrict__ hbL)       // [8 grp][4 phase][32 wg][64 u32]
{
  int wg  = blockIdx.x & 31;
  int bg  = (blockIdx.x >> 5) & 3;
  int dir = blockIdx.x >> 7;
  int grp = dir*4 + bg;
  const __half* xg = dir ? xgb : xgf;
  const float* wh  = dir ? whb : whf;
  const float* brc = dir ? brb : brf;
  unsigned* hbg = hbL + (size_t)grp*8192;   // 4*32*64 u32 = 32KB per group
  int tid = threadIdx.x;
  int u0 = wg*16, b0 = bg*8;
  int l = tid & 63, wv = tid >> 6;

  __shared__ _Float16 hsl[16*512];   // A-tile: rows 0..7 = batches, 8..15 dummy
  __shared__ float S[4*3*64*4];      // [kchunk][gate-tile][lane][q]

  // ---- B-frags: wave wv owns k-chunk wv*128; 3 tiles x 4 ksteps, 8 halfs each ----
  h8 wb[3][4];
  {
    int n = l & 15, kb = (l >> 4)*8;
#pragma unroll
    for (int t = 0; t < 3; t++) {
      int col = t*512 + u0 + n;
#pragma unroll
      for (int ks = 0; ks < 4; ks++) {
        int k0 = wv*128 + ks*32 + kb;
        h8 v;
#pragma unroll
        for (int j = 0; j < 8; j++)
          v[j] = (_Float16)wh[(size_t)(k0+j)*GG + col];
        wb[t][ks] = v;
      }
    }
  }
  // zero dummy A rows once (hygiene; their outputs are never read)
  for (int i = tid; i < 4096; i += 256)
    *(unsigned*)&hsl[8*512 + i*2] = 0u;

  // ---- gate thread state (tid<64): gb_=batch-in-group, up=u-pair ----
  int gb_ = tid >> 3, up = tid & 7;
  float br3[3][2];
  float hreg[2] = {0.f, 0.f};
  unsigned xzr = 0, xrr = 0, xhr = 0;
  if (tid < 64) {
    int u = u0 + up*2;
#pragma unroll
    for (int g = 0; g < 3; g++) { br3[g][0] = brc[g*512+u]; br3[g][1] = brc[g*512+u+1]; }
    // publish h0 = 0 into phase 0 (word 0x0 is valid data, != SENT)
    __hip_atomic_store(&hbg[(0*32 + wg)*64 + tid], 0u,
                       __ATOMIC_RELAXED, __HIP_MEMORY_SCOPE_AGENT);
    int t0_ = dir ? 511 : 0;
    const unsigned* xp = (const unsigned*)xg + (size_t)((b0+gb_)*TT + t0_)*768;
    xzr = xp[(u0>>1) + up];
    xrr = xp[256 + (u0>>1) + up];
    xhr = xp[512 + (u0>>1) + up];
  }

  // ---- stage helper mapping (tid 64..191): 32 regions x 4 threads x 64B ----
  int sidx = tid - 64, srw = sidx >> 2, sq = sidx & 3;

#define STAGE_PHASE(PH) {                                                   \
    const unsigned* gp = &hbg[((PH)*32 + srw)*64 + sq*16];                  \
    uint4 d0, d1, d2, d3;                                                   \
    long guard = 0;                                                         \
    for (;;) {                                                              \
      asm volatile(                                                         \
        "global_load_dwordx4 %0, %4, off sc0 sc1\n\t"                       \
        "global_load_dwordx4 %1, %4, off offset:16 sc0 sc1\n\t"             \
        "global_load_dwordx4 %2, %4, off offset:32 sc0 sc1\n\t"             \
        "global_load_dwordx4 %3, %4, off offset:48 sc0 sc1\n\t"             \
        "s_waitcnt vmcnt(0)"                                                \
        : "=&v"(d0),"=&v"(d1),"=&v"(d2),"=&v"(d3) : "v"(gp) : "memory");    \
      bool ok = (d0.x!=SENT)&(d0.y!=SENT)&(d0.z!=SENT)&(d0.w!=SENT)         \
              & (d1.x!=SENT)&(d1.y!=SENT)&(d1.z!=SENT)&(d1.w!=SENT)         \
              & (d2.x!=SENT)&(d2.y!=SENT)&(d2.z!=SENT)&(d2.w!=SENT)         \
              & (d3.x!=SENT)&(d3.y!=SENT)&(d3.z!=SENT)&(d3.w!=SENT);        \
      if (ok || ++guard > 3000000L) break;                                  \
    }                                                                       \
    int r0_ = sq*2, r1_ = sq*2 + 1, g0_ = srw*2;                            \
    *(uint4*)&hsl[r0_*512 + (((g0_  ) ^ r0_) << 3)] = d0;                   \
    *(uint4*)&hsl[r0_*512 + (((g0_+1) ^ r0_) << 3)] = d1;                   \
    *(uint4*)&hsl[r1_*512 + (((g0_  ) ^ r1_) << 3)] = d2;                   \
    *(uint4*)&hsl[r1_*512 + (((g0_+1) ^ r1_) << 3)] = d3;                   \
  }

  // prologue stage: bring phase-0 h (zeros) into hsl
  if (tid >= 64 && tid < 192) STAGE_PHASE(0);
  __syncthreads();

  for (int s = 0; s < 512; s++) {
    // ---- M: MFMA partials + S store; reset phase (s+2)&3 to sentinel ----
    f4 a0 = (f4){0.f,0.f,0.f,0.f}, a1 = a0, a2 = a0;
#pragma unroll
    for (int ks = 0; ks < 4; ks++) {
      int g = wv*16 + ks*4 + (l >> 4);
      h8 af = *(const h8*)&hsl[(l & 15)*512 + ((g ^ (l & 7)) << 3)];
      a0 = __builtin_amdgcn_mfma_f32_16x16x32_f16(af, wb[0][ks], a0, 0, 0, 0);
      a1 = __builtin_amdgcn_mfma_f32_16x16x32_f16(af, wb[1][ks], a1, 0, 0, 0);
      a2 = __builtin_amdgcn_mfma_f32_16x16x32_f16(af, wb[2][ks], a2, 0, 0, 0);
    }
    *(f4*)&S[((wv*3 + 0)*64 + l)*4] = a0;
    *(f4*)&S[((wv*3 + 1)*64 + l)*4] = a1;
    *(f4*)&S[((wv*3 + 2)*64 + l)*4] = a2;
    if (tid < 64)
      __hip_atomic_store(&hbg[(((s+2)&3)*32 + wg)*64 + tid], SENT,
                         __ATOMIC_RELAXED, __HIP_MEMORY_SCOPE_AGENT);
    __syncthreads();   // S visible; vmcnt drain orders reset before publish
    // ---- C: gates + publish (wave 0)  ||  stage s+1 (waves 1-2) ----
    int pn = (s + 1) & 3;
    if (tid < 64) {
      int lane_ = (gb_ >> 2)*16 + up*2;
      int q = gb_ & 3;
      float rgv[3][2];
#pragma unroll
      for (int g3 = 0; g3 < 3; g3++) {
#pragma unroll
        for (int e = 0; e < 2; e++) {
          float a = br3[g3][e];
#pragma unroll
          for (int w = 0; w < 4; w++)
            a += S[((w*3 + g3)*64 + lane_ + e)*4 + q];
          rgv[g3][e] = a;
        }
      }
      __half2 xzh = *(__half2*)&xzr, xrh = *(__half2*)&xrr, xhh = *(__half2*)&xhr;
      float2 xzv = __half22float2(xzh), xrv = __half22float2(xrh), xhv = __half22float2(xhh);
      float xzf[2] = {xzv.x, xzv.y}, xrf[2] = {xrv.x, xrv.y}, xhf[2] = {xhv.x, xhv.y};
#pragma unroll
      for (int e = 0; e < 2; e++) {
        float z = 1.f/(1.f + __expf(-(xzf[e] + rgv[0][e])));
        float r = 1.f/(1.f + __expf(-(xrf[e] + rgv[1][e])));
        float hh = fmaxf(xhf[e] + r*rgv[2][e], 0.f);
        hreg[e] = z*hreg[e] + (1.f - z)*hh;
      }
      __half2 hp2 = __floats2half2_rn(hreg[0], hreg[1]);
      unsigned pk = *(unsigned*)&hp2;
      __hip_atomic_store(&hbg[(pn*32 + wg)*64 + tid], pk,
                         __ATOMIC_RELAXED, __HIP_MEMORY_SCOPE_AGENT);
      int t = dir ? (511 - s) : s;
      ((unsigned*)H)[(size_t)((b0+gb_)*TT + t)*512 + dir*256 + (u0>>1) + up] = pk;
      int tn = (dir ? (510 - s) : (s + 1)) & 511;
      const unsigned* xp = (const unsigned*)xg + (size_t)((b0+gb_)*TT + tn)*768;
      xzr = xp[(u0>>1) + up];
      xrr = xp[256 + (u0>>1) + up];
      xhr = xp[512 + (u0>>1) + up];
    } else if (tid < 192) {
      STAGE_PHASE(pn);
    }
    __syncthreads();   // hsl(s+1) staged before next M
  }
#undef STAGE_PHASE
}

// ---------------- row softmax over V=1024, in place ----------------
__global__ __launch_bounds__(256) void softmax_k(float* __restrict__ p) {
  size_t row = blockIdx.x;
  float* pr = p + row*VV;
  int tid = threadIdx.x;
  float4 v = ((float4*)pr)[tid];
  float m = fmaxf(fmaxf(v.x, v.y), fmaxf(v.z, v.w));
#pragma unroll
  for (int o = 32; o >= 1; o >>= 1) m = fmaxf(m, __shfl_xor(m, o));
  __shared__ float red[4];
  __shared__ float red2[4];
  int w = tid >> 6;
  if ((tid & 63) == 0) red[w] = m;
  __syncthreads();
  m = fmaxf(fmaxf(red[0], red[1]), fmaxf(red[2], red[3]));
  v.x = __expf(v.x - m); v.y = __expf(v.y - m);
  v.z = __expf(v.z - m); v.w = __expf(v.w - m);
  float s = v.x + v.y + v.z + v.w;
#pragma unroll
  for (int o = 32; o >= 1; o >>= 1) s += __shfl_xor(s, o);
  if ((tid & 63) == 0) red2[w] = s;
  __syncthreads();
  s = red2[0] + red2[1] + red2[2] + red2[3];
  float inv = 1.f / s;
  v.x *= inv; v.y *= inv; v.z *= inv; v.w *= inv;
  ((float4*)pr)[tid] = v;
}

extern "C" void kernel_launch(void* const* d_in, const int* in_sizes, int n_in,
                              void* d_out, int out_size, void* d_ws, size_t ws_size,
                              hipStream_t stream) {
  const float* x      = (const float*)d_in[0];
  const float* conv_w = (const float*)d_in[1];
  const float* conv_b = (const float*)d_in[2];
  const float* wx_f   = (const float*)d_in[3];
  const float* wh_f   = (const float*)d_in[4];
  const float* bi_f   = (const float*)d_in[5];
  const float* br_f   = (const float*)d_in[6];
  const float* wx_b   = (const float*)d_in[7];
  const float* wh_b   = (const float*)d_in[8];
  const float* bi_b   = (const float*)d_in[9];
  const float* br_b   = (const float*)d_in[10];
  const float* gam    = (const float*)d_in[11];
  const float* bet    = (const float*)d_in[12];
  const float* mu_    = (const float*)d_in[13];
  const float* var_   = (const float*)d_in[14];
  const float* dw     = (const float*)d_in[15];
  const float* db     = (const float*)d_in[16];

  char* ws = (char*)d_ws;
  __half* xgf   = (__half*)(ws + 0);
  __half* xgb   = (__half*)(ws + 50331648LL);
  __half* WxfT2 = (__half*)(ws + 100663296LL);
  __half* WxbT2 = (__half*)(ws + 103809024LL);
  __half* DwT2  = (__half*)(ws + 106954752LL);
  float*  bias2 = (float*)(ws + 109051904LL);
  __half* c0    = (__half*)(ws + 109056000LL);
  __half* H     = (__half*)(ws + 109056000LL);   // overlays c0 (c0 dead before H written)
  unsigned* hb1 = (unsigned*)(ws + 142610432LL); // 256 KB (layer 1 exchange)
  unsigned* hb2 = (unsigned*)(ws + 142872576LL); // 256 KB (layer 2 exchange)
  if (ws_size < 143134720ULL) return;
  float* logits = (float*)d_out;

  // sentinel-fill both layers' exchange buffers (0xFF bytes = f16 NaN pairs)
  hipMemsetAsync(hb1, 0xFF, 524288, stream);

  prep_wx_k<<<dim3(8,24,2), 256, 0, stream>>>(wx_f, wx_b, WxfT2, WxbT2);
  prep_dense_k<<<dim3(8,16), 256, 0, stream>>>(dw, gam, var_, DwT2);
  prep_bias_k<<<4, 256, 0, stream>>>(dw, db, gam, bet, mu_, var_, bias2);

  conv_bn_k<<<dim3(32,32,2), 256, 0, stream>>>(x, conv_w, conv_b, gam, bet, mu_, var_, c0);

  hgemm_k<1><<<dim3(12,128), 256, 0, stream>>>(c0, WxfT2, bi_f, xgf, MM, GG, 512, 512, 1024);
  hgemm_k<1><<<dim3(12,128), 256, 0, stream>>>(c0, WxbT2, bi_b, xgb, MM, GG, 512, 512, 1024);
  gru_layer_k<<<256, 256, 0, stream>>>(xgf, xgb, wh_f, wh_b, br_f, br_b, H, hb1);
  hgemm_k<1><<<dim3(12,128), 256, 0, stream>>>(H, WxfT2, bi_f, xgf, MM, GG, 1024, 1024, 1024);
  hgemm_k<1><<<dim3(12,128), 256, 0, stream>>>(H, WxbT2, bi_b, xgb, MM, GG, 1024, 1024, 1024);
  gru_layer_k<<<256, 256, 0, stream>>>(xgf, xgb, wh_f, wh_b, br_f, br_b, H, hb2);
  hgemm_k<0><<<dim3(8,128), 256, 0, stream>>>(H, DwT2, bias2, logits, MM, VV, 1024, 1024, 1024);
  softmax_k<<<MM, 256, 0, stream>>>(logits);
}

// Round 8
// 2830.155 us; speedup vs baseline: 3.8485x; 1.0212x over previous
//
#include <hip/hip_runtime.h>
#include <hip/hip_fp16.h>

#define BB 32
#define CC 512
#define UU 512
#define GG 1536
#define VV 1024
#define TT 512
#define MM (BB*TT)   // 16384
#define TIN 1024
#define FIN 80
#define EPS 1e-3f
#define SENT 0xFFFFFFFFu   // two f16 NaNs — impossible as finite GRU output

typedef _Float16 h8 __attribute__((ext_vector_type(8)));
typedef float f4 __attribute__((ext_vector_type(4)));

// ---------------- conv1d(stride2,SAME) + bias + relu + BN -> f16 ----------------
__global__ __launch_bounds__(256) void conv_bn_k(
    const float* __restrict__ x, const float* __restrict__ w, const float* __restrict__ cb,
    const float* __restrict__ gam, const float* __restrict__ bet,
    const float* __restrict__ mu_, const float* __restrict__ var_,
    __half* __restrict__ out)
{
  __shared__ float xs[41*80];
  int tg = blockIdx.x, b = blockIdx.y, ch = blockIdx.z;
  int t0 = tg*16;
  int in0 = t0*2 - 4;
  for (int i = threadIdx.x; i < 41*80; i += 256) {
    int r = i / 80, f = i - r*80;
    int ri = in0 + r;
    xs[i] = (ri >= 0 && ri < TIN) ? x[((size_t)b*TIN + ri)*FIN + f] : 0.f;
  }
  __syncthreads();
  int c = ch*256 + threadIdx.x;
  float acc[16];
  float bv = cb[c];
#pragma unroll
  for (int i = 0; i < 16; i++) acc[i] = bv;
  for (int k = 0; k < 11; k++) {
    for (int f = 0; f < 80; f++) {
      float wv = w[((size_t)k*80 + f)*CC + c];
#pragma unroll
      for (int i = 0; i < 16; i++) acc[i] += xs[(2*i + k)*80 + f] * wv;
    }
  }
  float ga = gam[c], be = bet[c], mu = mu_[c], iv = rsqrtf(var_[c] + EPS);
#pragma unroll
  for (int i = 0; i < 16; i++) {
    float v = fmaxf(acc[i], 0.f);
    out[((size_t)b*TT + t0 + i)*CC + c] = __float2half(ga*(v - mu)*iv + be);
  }
}

// -------- prep: transpose+cvt Wx (512x1536 f32) -> WxT2 (1536 x 1024 f16, k dup) --------
__global__ __launch_bounds__(256) void prep_wx_k(
    const float* __restrict__ wxf, const float* __restrict__ wxb,
    __half* __restrict__ of, __half* __restrict__ ob)
{
  __shared__ float tile[64][65];
  int kt = blockIdx.x*64, nt = blockIdx.y*64;
  const float* src = blockIdx.z ? wxb : wxf;
  __half* dst = blockIdx.z ? ob : of;
  for (int i = threadIdx.x; i < 4096; i += 256) {
    int r = i >> 6, c = i & 63;
    tile[r][c] = src[(size_t)(kt+r)*GG + nt + c];
  }
  __syncthreads();
  for (int i = threadIdx.x; i < 4096; i += 256) {
    int r = i >> 6, c = i & 63;          // r = n, c = k
    __half h = __float2half(tile[c][r]);
    dst[(size_t)(nt+r)*1024 + kt + c] = h;
    dst[(size_t)(nt+r)*1024 + 512 + kt + c] = h;
  }
}

// -------- prep: dense_w (512x1024) scaled by BN gamma*rsqrt -> DwT2 (1024x1024 f16, dup) --------
__global__ __launch_bounds__(256) void prep_dense_k(
    const float* __restrict__ dw, const float* __restrict__ gam, const float* __restrict__ var_,
    __half* __restrict__ dst)
{
  __shared__ float tile[64][65];
  __shared__ float s64[64];
  int kt = blockIdx.x*64, nt = blockIdx.y*64;
  if (threadIdx.x < 64) {
    int k = kt + threadIdx.x;
    s64[threadIdx.x] = gam[k] * rsqrtf(var_[k] + EPS);
  }
  for (int i = threadIdx.x; i < 4096; i += 256) {
    int r = i >> 6, c = i & 63;
    tile[r][c] = dw[(size_t)(kt+r)*VV + nt + c];
  }
  __syncthreads();
  for (int i = threadIdx.x; i < 4096; i += 256) {
    int r = i >> 6, c = i & 63;          // r = n, c = k
    __half h = __float2half(tile[c][r] * s64[c]);
    dst[(size_t)(nt+r)*1024 + kt + c] = h;
    dst[(size_t)(nt+r)*1024 + 512 + kt + c] = h;
  }
}

// -------- prep: bias2[n] = db[n] + sum_k (bet - gam*mu*rs)[k] * dw[k][n] --------
__global__ __launch_bounds__(256) void prep_bias_k(
    const float* __restrict__ dw, const float* __restrict__ db,
    const float* __restrict__ gam, const float* __restrict__ bet,
    const float* __restrict__ mu_, const float* __restrict__ var_,
    float* __restrict__ bias2)
{
  int n = blockIdx.x*256 + threadIdx.x;
  float acc = db[n];
  for (int k = 0; k < CC; k++) {
    float o = bet[k] - gam[k]*mu_[k]*rsqrtf(var_[k] + EPS);
    acc += o * dw[(size_t)k*VV + n];
  }
  bias2[n] = acc;
}

// ---------------- f16 MFMA GEMM: C[M,N] = A[M,K](f16,lda) @ BT[N,K]^T(f16,ldb) + bias ----------------
template<int OUTH>
__global__ __launch_bounds__(256,2) void hgemm_k(
    const __half* __restrict__ A, const __half* __restrict__ BT,
    const float* __restrict__ bias, void* __restrict__ Cout,
    int M, int N, int K, int lda, int ldb)
{
  __shared__ _Float16 As[128*40];
  __shared__ _Float16 Bs[128*40];
  int m0 = blockIdx.y*128, n0 = blockIdx.x*128;
  int tid = threadIdx.x;
  int l = tid & 63, w = tid >> 6;
  int wr = w >> 1, wc = w & 1;
  int srow = tid >> 1, soff = (tid & 1)*16;
  const __half* ap = A  + (size_t)(m0 + srow)*lda + soff;
  const __half* bp = BT + (size_t)(n0 + srow)*ldb + soff;
  f4 acc[4][4];
#pragma unroll
  for (int i=0;i<4;i++)
#pragma unroll
    for (int j=0;j<4;j++) acc[i][j] = (f4){0.f,0.f,0.f,0.f};

  uint4 av  = *(const uint4*)(ap);
  uint4 av2 = *(const uint4*)(ap + 8);
  uint4 bv  = *(const uint4*)(bp);
  uint4 bv2 = *(const uint4*)(bp + 8);
  int lr = (l & 15), lk = (l >> 4)*8;
  for (int k0 = 0; k0 < K; k0 += 32) {
    __syncthreads();
    *(uint4*)&As[srow*40 + soff]     = av;
    *(uint4*)&As[srow*40 + soff + 8] = av2;
    *(uint4*)&Bs[srow*40 + soff]     = bv;
    *(uint4*)&Bs[srow*40 + soff + 8] = bv2;
    __syncthreads();
    if (k0 + 32 < K) {
      av  = *(const uint4*)(ap + k0 + 32);
      av2 = *(const uint4*)(ap + k0 + 40);
      bv  = *(const uint4*)(bp + k0 + 32);
      bv2 = *(const uint4*)(bp + k0 + 40);
    }
    h8 af[4], bf[4];
#pragma unroll
    for (int i = 0; i < 4; i++)
      af[i] = *(const h8*)&As[(wr*64 + i*16 + lr)*40 + lk];
#pragma unroll
    for (int j = 0; j < 4; j++)
      bf[j] = *(const h8*)&Bs[(wc*64 + j*16 + lr)*40 + lk];
#pragma unroll
    for (int i = 0; i < 4; i++)
#pragma unroll
      for (int j = 0; j < 4; j++)
        acc[i][j] = __builtin_amdgcn_mfma_f32_16x16x32_f16(af[i], bf[j], acc[i][j], 0, 0, 0);
  }
  int cb = n0 + wc*64 + lr;
  int rb = m0 + wr*64 + (l >> 4)*4;
#pragma unroll
  for (int j = 0; j < 4; j++) {
    float bs = bias[cb + j*16];
#pragma unroll
    for (int i = 0; i < 4; i++) {
#pragma unroll
      for (int q = 0; q < 4; q++) {
        float v = acc[i][j][q] + bs;
        int row = rb + i*16 + q, col = cb + j*16;
        if (OUTH) ((__half*)Cout)[(size_t)row*N + col] = __float2half(v);
        else      ((float*)Cout)[(size_t)row*N + col] = v;
      }
    }
  }
}

// ---------------- persistent bidirectional GRU layer (wave-local gates) ----------
// 64 WGs = 2 dir x 4 batch-groups x 8 WGs. WG owns 64 u (wave owns 16 u).
// Swapped MFMA: A = Wh^T (regs, 192 VGPR/lane), B = h^T (LDS). D[row=u][col=b]
// -> all 3 gate accs lane-local (lane=batch, q=4 u's). No cross-wave reduce,
// 1 barrier/step, double-buffered hsl. h exchange: 4-phase sentinel regions
// (1KB/WG), poll-data-directly sc0sc1; reset targets phase (s+3)&3 (ordering
// carried transitively through end-of-step barrier + observed publishes).
__global__ __launch_bounds__(256,1) void gru_layer_k(
    const __half* __restrict__ xgf, const __half* __restrict__ xgb,
    const float* __restrict__ whf, const float* __restrict__ whb,
    const float* __restrict__ brf, const float* __restrict__ brb,
    __half* __restrict__ H,           // [16384][1024], cols dir*512+u
    unsigned* __restrict__ hbL)       // [8 grp][4 phase][8 wg][256 u32]
{
  int wg  = blockIdx.x & 7;
  int bg  = (blockIdx.x >> 3) & 3;
  int dir = blockIdx.x >> 5;
  int grp = dir*4 + bg;
  const __half* xg = dir ? xgb : xgf;
  const float* wh  = dir ? whb : whf;
  const float* brc = dir ? brb : brf;
  unsigned* hbg = hbL + (size_t)grp*8192;   // 4*8*256 u32 = 32KB per group
  int tid = threadIdx.x;
  int L = tid & 63, wv = tid >> 6;
  int u0 = wg*64, b0 = bg*8;

  __shared__ _Float16 hsl[2][8][512];   // [buf][batch][u], granule-swizzled g^b

  // ---- A-frags: Wh^T slice in regs. lane: row u=(L&15), k-block kb=(L>>4) ----
  int urow = L & 15, kb = L >> 4;
  int ubase = u0 + wv*16;
  h8 wb[3][16];
#pragma unroll
  for (int g3 = 0; g3 < 3; g3++)
#pragma unroll
    for (int ks = 0; ks < 16; ks++) {
      h8 v;
#pragma unroll
      for (int j = 0; j < 8; j++)
        v[j] = (_Float16)wh[(size_t)(ks*32 + kb*8 + j)*GG + g3*512 + ubase + urow];
      wb[g3][ks] = v;
    }

  // ---- per-lane gate state: batch b=(L&15) [valid<8], 4 u's = ubase+kb*4+q ----
  int b = L & 15, b7 = L & 7;
  int myu = ubase + kb*4;
  float br3[3][4];
#pragma unroll
  for (int g3 = 0; g3 < 3; g3++)
#pragma unroll
    for (int q = 0; q < 4; q++)
      br3[g3][q] = brc[g3*512 + myu + q];
  float hreg[4] = {0.f, 0.f, 0.f, 0.f};
  bool bval = b < 8;
  int upair = (u0 >> 1) + wv*8 + kb*2;     // u32-pair index of myu within dir half

  // xg prefetch for s=0
  uint2 xz2, xr2, xh2;
  {
    int t0_ = dir ? 511 : 0;
    const unsigned* xp = (const unsigned*)xg + (size_t)((b0 + b7)*TT + t0_)*768;
    xz2 = *(const uint2*)(xp + upair);
    xr2 = *(const uint2*)(xp + 256 + upair);
    xh2 = *(const uint2*)(xp + 512 + upair);
  }

  // ---- init: publish h0 = 0 into phase 0 own region ----
  __hip_atomic_store(&hbg[0*2048 + wg*256 + tid], 0u,
                     __ATOMIC_RELAXED, __HIP_MEMORY_SCOPE_AGENT);

  // stage mapping: thread t: region r=t>>5 (8 wg), chunk c=t&31 (32B each)
  int sr = tid >> 5, sc = tid & 31;
  int sb = sc >> 2, sg0 = sr*8 + (sc & 3)*2;
  int sws0 = ((sg0 ^ sb) << 3), sws1 = (((sg0 + 1) ^ sb) << 3);

#define STAGE(PH, NB) {                                                     \
    const unsigned* gp = &hbg[(PH)*2048 + sr*256 + sc*8];                   \
    uint4 d0, d1;                                                           \
    long guard = 0;                                                         \
    for (;;) {                                                              \
      asm volatile(                                                         \
        "global_load_dwordx4 %0, %2, off sc0 sc1\n\t"                       \
        "global_load_dwordx4 %1, %2, off offset:16 sc0 sc1\n\t"             \
        "s_waitcnt vmcnt(0)"                                                \
        : "=&v"(d0), "=&v"(d1) : "v"(gp) : "memory");                       \
      bool ok = (d0.x!=SENT)&(d0.y!=SENT)&(d0.z!=SENT)&(d0.w!=SENT)         \
              & (d1.x!=SENT)&(d1.y!=SENT)&(d1.z!=SENT)&(d1.w!=SENT);        \
      if (ok || ++guard > 3000000L) break;                                  \
    }                                                                       \
    *(uint4*)&hsl[NB][sb][sws0] = d0;                                       \
    *(uint4*)&hsl[NB][sb][sws1] = d1;                                       \
  }

  // prologue: stage phase 0 (zeros) into hsl[0]
  STAGE(0, 0);
  __syncthreads();

  for (int s = 0; s < 512; s++) {
    int buf = s & 1;
    // reset own region of phase (s+3)&3 (provably dead; see header comment)
    __hip_atomic_store(&hbg[((s+3)&3)*2048 + wg*256 + tid], SENT,
                       __ATOMIC_RELAXED, __HIP_MEMORY_SCOPE_AGENT);
    // ---- M: 16 ds_read_b128 + 48 MFMA (k=512, 3 gates), all in-wave ----
    f4 a0 = (f4){0.f,0.f,0.f,0.f}, a1 = a0, a2 = a0;
#pragma unroll
    for (int ks = 0; ks < 16; ks++) {
      int g = ks*4 + kb;
      h8 hf = *(const h8*)&hsl[buf][b7][(g ^ b7) << 3];
      a0 = __builtin_amdgcn_mfma_f32_16x16x32_f16(wb[0][ks], hf, a0, 0, 0, 0);
      a1 = __builtin_amdgcn_mfma_f32_16x16x32_f16(wb[1][ks], hf, a1, 0, 0, 0);
      a2 = __builtin_amdgcn_mfma_f32_16x16x32_f16(wb[2][ks], hf, a2, 0, 0, 0);
    }
    // ---- gates: lane-local (batch=b, u=myu+q); D row=kb*4+q matches q ----
    int t = dir ? (511 - s) : s;
    __half2 xzl = *(__half2*)&xz2.x, xzh = *(__half2*)&xz2.y;
    __half2 xrl = *(__half2*)&xr2.x, xrh = *(__half2*)&xr2.y;
    __half2 xhl = *(__half2*)&xh2.x, xhh = *(__half2*)&xh2.y;
    float2 fz0 = __half22float2(xzl), fz1 = __half22float2(xzh);
    float2 fr0 = __half22float2(xrl), fr1 = __half22float2(xrh);
    float2 fh0 = __half22float2(xhl), fh1 = __half22float2(xhh);
    float xzf[4] = {fz0.x, fz0.y, fz1.x, fz1.y};
    float xrf[4] = {fr0.x, fr0.y, fr1.x, fr1.y};
    float xhf[4] = {fh0.x, fh0.y, fh1.x, fh1.y};
#pragma unroll
    for (int q = 0; q < 4; q++) {
      float az = (q==0? a0[0] : q==1? a0[1] : q==2? a0[2] : a0[3]);
      float ar = (q==0? a1[0] : q==1? a1[1] : q==2? a1[2] : a1[3]);
      float ah = (q==0? a2[0] : q==1? a2[1] : q==2? a2[2] : a2[3]);
      float z = 1.f/(1.f + __expf(-(xzf[q] + br3[0][q] + az)));
      float r = 1.f/(1.f + __expf(-(xrf[q] + br3[1][q] + ar)));
      float hh = fmaxf(xhf[q] + r*(br3[2][q] + ah), 0.f);
      hreg[q] = z*hreg[q] + (1.f - z)*hh;
    }
    int pn = (s + 1) & 3;
    if (bval) {
      __half2 p01 = __floats2half2_rn(hreg[0], hreg[1]);
      __half2 p23 = __floats2half2_rn(hreg[2], hreg[3]);
      unsigned pk0 = *(unsigned*)&p01, pk1 = *(unsigned*)&p23;
      unsigned long pkl = ((unsigned long)pk1 << 32) | pk0;
      __hip_atomic_store((unsigned long*)&hbg[pn*2048 + wg*256 + b*32 + wv*8 + kb*2],
                         pkl, __ATOMIC_RELAXED, __HIP_MEMORY_SCOPE_AGENT);
      uint2 pv; pv.x = pk0; pv.y = pk1;
      *(uint2*)((unsigned*)H + (size_t)((b0 + b)*TT + t)*512 + dir*256 + upair) = pv;
    }
    // xg prefetch for s+1
    {
      int tn = (dir ? (510 - s) : (s + 1)) & 511;
      const unsigned* xp = (const unsigned*)xg + (size_t)((b0 + b7)*TT + tn)*768;
      xz2 = *(const uint2*)(xp + upair);
      xr2 = *(const uint2*)(xp + 256 + upair);
      xh2 = *(const uint2*)(xp + 512 + upair);
    }
    // ---- stage phase (s+1)&3 into hsl[buf^1] ----
    if (s < 511) STAGE(pn, buf ^ 1);
    __syncthreads();
  }
#undef STAGE
}

// ---------------- row softmax over V=1024, in place ----------------
__global__ __launch_bounds__(256) void softmax_k(float* __restrict__ p) {
  size_t row = blockIdx.x;
  float* pr = p + row*VV;
  int tid = threadIdx.x;
  float4 v = ((float4*)pr)[tid];
  float m = fmaxf(fmaxf(v.x, v.y), fmaxf(v.z, v.w));
#pragma unroll
  for (int o = 32; o >= 1; o >>= 1) m = fmaxf(m, __shfl_xor(m, o));
  __shared__ float red[4];
  __shared__ float red2[4];
  int w = tid >> 6;
  if ((tid & 63) == 0) red[w] = m;
  __syncthreads();
  m = fmaxf(fmaxf(red[0], red[1]), fmaxf(red[2], red[3]));
  v.x = __expf(v.x - m); v.y = __expf(v.y - m);
  v.z = __expf(v.z - m); v.w = __expf(v.w - m);
  float s = v.x + v.y + v.z + v.w;
#pragma unroll
  for (int o = 32; o >= 1; o >>= 1) s += __shfl_xor(s, o);
  if ((tid & 63) == 0) red2[w] = s;
  __syncthreads();
  s = red2[0] + red2[1] + red2[2] + red2[3];
  float inv = 1.f / s;
  v.x *= inv; v.y *= inv; v.z *= inv; v.w *= inv;
  ((float4*)pr)[tid] = v;
}

extern "C" void kernel_launch(void* const* d_in, const int* in_sizes, int n_in,
                              void* d_out, int out_size, void* d_ws, size_t ws_size,
                              hipStream_t stream) {
  const float* x      = (const float*)d_in[0];
  const float* conv_w = (const float*)d_in[1];
  const float* conv_b = (const float*)d_in[2];
  const float* wx_f   = (const float*)d_in[3];
  const float* wh_f   = (const float*)d_in[4];
  const float* bi_f   = (const float*)d_in[5];
  const float* br_f   = (const float*)d_in[6];
  const float* wx_b   = (const float*)d_in[7];
  const float* wh_b   = (const float*)d_in[8];
  const float* bi_b   = (const float*)d_in[9];
  const float* br_b   = (const float*)d_in[10];
  const float* gam    = (const float*)d_in[11];
  const float* bet    = (const float*)d_in[12];
  const float* mu_    = (const float*)d_in[13];
  const float* var_   = (const float*)d_in[14];
  const float* dw     = (const float*)d_in[15];
  const float* db     = (const float*)d_in[16];

  char* ws = (char*)d_ws;
  __half* xgf   = (__half*)(ws + 0);
  __half* xgb   = (__half*)(ws + 50331648LL);
  __half* WxfT2 = (__half*)(ws + 100663296LL);
  __half* WxbT2 = (__half*)(ws + 103809024LL);
  __half* DwT2  = (__half*)(ws + 106954752LL);
  float*  bias2 = (float*)(ws + 109051904LL);
  __half* c0    = (__half*)(ws + 109056000LL);
  __half* H     = (__half*)(ws + 109056000LL);   // overlays c0 (c0 dead before H written)
  unsigned* hb1 = (unsigned*)(ws + 142610432LL); // 256 KB (layer 1 exchange)
  unsigned* hb2 = (unsigned*)(ws + 142872576LL); // 256 KB (layer 2 exchange)
  if (ws_size < 143134720ULL) return;
  float* logits = (float*)d_out;

  // sentinel-fill both layers' exchange buffers (0xFF bytes = f16 NaN pairs)
  hipMemsetAsync(hb1, 0xFF, 524288, stream);

  prep_wx_k<<<dim3(8,24,2), 256, 0, stream>>>(wx_f, wx_b, WxfT2, WxbT2);
  prep_dense_k<<<dim3(8,16), 256, 0, stream>>>(dw, gam, var_, DwT2);
  prep_bias_k<<<4, 256, 0, stream>>>(dw, db, gam, bet, mu_, var_, bias2);

  conv_bn_k<<<dim3(32,32,2), 256, 0, stream>>>(x, conv_w, conv_b, gam, bet, mu_, var_, c0);

  hgemm_k<1><<<dim3(12,128), 256, 0, stream>>>(c0, WxfT2, bi_f, xgf, MM, GG, 512, 512, 1024);
  hgemm_k<1><<<dim3(12,128), 256, 0, stream>>>(c0, WxbT2, bi_b, xgb, MM, GG, 512, 512, 1024);
  gru_layer_k<<<64, 256, 0, stream>>>(xgf, xgb, wh_f, wh_b, br_f, br_b, H, hb1);
  hgemm_k<1><<<dim3(12,128), 256, 0, stream>>>(H, WxfT2, bi_f, xgf, MM, GG, 1024, 1024, 1024);
  hgemm_k<1><<<dim3(12,128), 256, 0, stream>>>(H, WxbT2, bi_b, xgb, MM, GG, 1024, 1024, 1024);
  gru_layer_k<<<64, 256, 0, stream>>>(xgf, xgb, wh_f, wh_b, br_f, br_b, H, hb2);
  hgemm_k<0><<<dim3(8,128), 256, 0, stream>>>(H, DwT2, bias2, logits, MM, VV, 1024, 1024, 1024);
  softmax_k<<<MM, 256, 0, stream>>>(logits);
}